// Round 1
// baseline (341.732 us; speedup 1.0000x reference)
//
#include <hip/hip_runtime.h>
#include <math.h>

#define NB 2
#define NN 4096
#define NK 512
#define NC 384
#define NR 16
#define NCH 192

static constexpr float INV_SQRT_C = 0.051031036307982884f; // 1/sqrt(384)
static constexpr float TWO_PI     = 6.283185307179586f;
static constexpr float F_JITTER   = 1e-4f;

// ---------------- kernel 1: per-batch node_mask sum ----------------
__global__ __launch_bounds__(256) void k_masksum(const float* __restrict__ node_mask,
                                                 float* __restrict__ Lsum) {
    int b = blockIdx.x, t = threadIdx.x;
    __shared__ float red[256];
    float s = 0.f;
    for (int n = t; n < NN; n += 256) s += node_mask[b*NN + n];
    red[t] = s; __syncthreads();
    for (int w = 128; w > 0; w >>= 1) { if (t < w) red[t] += red[t+w]; __syncthreads(); }
    if (t == 0) Lsum[b] = red[0];
}

// ---------------- kernel 2: fourier emb + layernorm -> q0 ----------------
__global__ __launch_bounds__(128) void k_q0(const int* __restrict__ res_idx,
                                            const float* __restrict__ node_mask,
                                            const float* __restrict__ Bm,
                                            const float* __restrict__ ln_g,
                                            const float* __restrict__ ln_b,
                                            const float* __restrict__ Lsum,
                                            float* __restrict__ q0) {
    int row = blockIdx.x, t = threadIdx.x;
    int b = row >> 12;
    __shared__ float emb[NC];
    __shared__ float red[128];
    float m = node_mask[row];
    float Lb = fmaxf(Lsum[b], 1.0f);
    float denom = fmaxf(Lb - 1.0f, 1.0f);
    int ri = res_idx[row];
    ri = ri < 0 ? 0 : (ri > 4095 ? 4095 : ri);
    float pos = fminf(fmaxf((float)ri / denom, 0.f), 1.f);
    for (int i = t; i < NCH; i += 128) {
        float pr = TWO_PI * pos * Bm[i];
        emb[i]      = cosf(pr) * m;
        emb[i+NCH]  = sinf(pr) * m;
    }
    __syncthreads();
    float e0 = emb[t], e1 = emb[t+128], e2 = emb[t+256];
    red[t] = e0 + e1 + e2; __syncthreads();
    for (int w = 64; w > 0; w >>= 1) { if (t < w) red[t] += red[t+w]; __syncthreads(); }
    float mean = red[0] * (1.0f/NC);
    __syncthreads();
    float d0 = e0-mean, d1 = e1-mean, d2 = e2-mean;
    red[t] = d0*d0 + d1*d1 + d2*d2; __syncthreads();
    for (int w = 64; w > 0; w >>= 1) { if (t < w) red[t] += red[t+w]; __syncthreads(); }
    float var = red[0] * (1.0f/NC);
    float inv = 1.0f / sqrtf(var + 1e-5f);
    q0[(size_t)row*NC + t]       = d0*inv*ln_g[t]      + ln_b[t];
    q0[(size_t)row*NC + t + 128] = d1*inv*ln_g[t+128]  + ln_b[t+128];
    q0[(size_t)row*NC + t + 256] = d2*inv*ln_g[t+256]  + ln_b[t+256];
}

// ---------------- kernel 3: generic [M,384]@[384,384] fp32 GEMM ----------------
__global__ __launch_bounds__(256) void k_gemm384(const float* __restrict__ A,
                                                 const float* __restrict__ W,
                                                 float* __restrict__ out) {
    __shared__ float As[16][68];
    __shared__ float Ws[16][68];
    int t = threadIdx.x;
    int tx = t & 15, ty = t >> 4;
    int rowbase = blockIdx.x * 64, colbase = blockIdx.y * 64;
    float acc[4][4] = {};
    for (int k0 = 0; k0 < NC; k0 += 16) {
        {
            int r = t >> 2, ja = (t & 3) << 2;
            float4 a4 = *(const float4*)(A + (size_t)(rowbase + r)*NC + k0 + ja);
            As[ja+0][r] = a4.x; As[ja+1][r] = a4.y; As[ja+2][r] = a4.z; As[ja+3][r] = a4.w;
        }
        {
            int kr = t >> 4, jw = (t & 15) << 2;
            float4 w4 = *(const float4*)(W + (size_t)(k0 + kr)*NC + colbase + jw);
            *(float4*)&Ws[kr][jw] = w4;
        }
        __syncthreads();
        #pragma unroll
        for (int kk = 0; kk < 16; ++kk) {
            float4 av = *(const float4*)&As[kk][ty<<2];
            float4 wv = *(const float4*)&Ws[kk][tx<<2];
            float aa[4] = {av.x, av.y, av.z, av.w};
            float ww[4] = {wv.x, wv.y, wv.z, wv.w};
            #pragma unroll
            for (int i = 0; i < 4; ++i)
                #pragma unroll
                for (int j = 0; j < 4; ++j)
                    acc[i][j] += aa[i]*ww[j];
        }
        __syncthreads();
    }
    #pragma unroll
    for (int i = 0; i < 4; ++i) {
        float4 o = make_float4(acc[i][0], acc[i][1], acc[i][2], acc[i][3]);
        *(float4*)(out + (size_t)(rowbase + (ty<<2) + i)*NC + colbase + (tx<<2)) = o;
    }
}

// ---------------- kernel 4: K x K overlap scores + top-16 per row ----------------
__global__ __launch_bounds__(256) void k_score_topk(const float* __restrict__ mu,
                                                    const float* __restrict__ Sg,
                                                    const float* __restrict__ maskp,
                                                    int* __restrict__ knn) {
    int b = blockIdx.x >> 9, i = blockIdx.x & 511;
    int t = threadIdx.x;
    __shared__ float sc[NK];
    __shared__ float rv[256];
    __shared__ int   rix[256];
    const float* mui = mu + (size_t)(b*NK + i)*3;
    const float* Sgi = Sg + (size_t)(b*NK + i)*9;
    float mi0 = mui[0], mi1 = mui[1], mi2 = mui[2];
    float S0 = Sgi[0], S1 = Sgi[1], S2 = Sgi[2], S4 = Sgi[4], S5 = Sgi[5], S8 = Sgi[8];
    float mski = maskp[b*NK + i];
    for (int j = t; j < NK; j += 256) {
        const float* muj = mu + (size_t)(b*NK + j)*3;
        const float* Sgj = Sg + (size_t)(b*NK + j)*9;
        float d0 = mi0-muj[0], d1 = mi1-muj[1], d2 = mi2-muj[2];
        float a00 = S0+Sgj[0]+1e-6f, a01 = S1+Sgj[1],       a02 = S2+Sgj[2];
        float a11 = S4+Sgj[4]+1e-6f, a12 = S5+Sgj[5],       a22 = S8+Sgj[8]+1e-6f;
        float c00 = a11*a22 - a12*a12;
        float c01 = a02*a12 - a01*a22;
        float c02 = a01*a12 - a02*a11;
        float c11 = a00*a22 - a02*a02;
        float c12 = a01*a02 - a00*a12;
        float c22 = a00*a11 - a01*a01;
        float det = a00*c00 + a01*c01 + a02*c02;
        float t0 = c00*d0 + c01*d1 + c02*d2;
        float t1 = c01*d0 + c11*d1 + c12*d2;
        float t2 = c02*d0 + c12*d1 + c22*d2;
        float maha = (d0*t0 + d1*t1 + d2*t2) / det;
        float score = -0.5f*(maha + logf(det));
        float mj = maskp[b*NK + j];
        if (mski*mj < 0.5f) score = -1e9f;
        sc[j] = score;
    }
    __syncthreads();
    for (int it = 0; it < NR; ++it) {
        float best = -INFINITY; int bi = 0;
        for (int j = t; j < NK; j += 256) {     // ascending j: strict > keeps first max
            float v = sc[j];
            if (v > best) { best = v; bi = j; }
        }
        rv[t] = best; rix[t] = bi;
        __syncthreads();
        for (int w = 128; w > 0; w >>= 1) {
            if (t < w) {
                float v2 = rv[t+w]; int i2 = rix[t+w];
                if (v2 > rv[t] || (v2 == rv[t] && i2 < rix[t])) { rv[t] = v2; rix[t] = i2; }
            }
            __syncthreads();
        }
        if (t == 0) { knn[((size_t)(b*NK + i))*NR + it] = rix[0]; sc[rix[0]] = -INFINITY; }
        __syncthreads();
    }
}

// ---------------- kernel 5: logits_full (16 rows x 512 parents / block) + argmax ----------------
__global__ __launch_bounds__(256) void k_logits_argmax(const float* __restrict__ q,
                                                       const float* __restrict__ kmat,
                                                       const float* __restrict__ maskp,
                                                       int* __restrict__ j0) {
    int t = threadIdx.x;
    int rowbase = blockIdx.x << 4;
    int b = rowbase >> 12;
    __shared__ float kkT[16][NK];      // [c][p] transposed k chunk
    __shared__ float qqT[16][20];      // [c][row]
    __shared__ float sv[16][128];
    __shared__ int   si[16][128];
    int pg = t & 127, rg = t >> 7;     // 4 parents x 8 rows per thread
    float acc[8][4] = {};
    const float* kb = kmat + (size_t)b*NK*NC;
    for (int c0 = 0; c0 < NC; c0 += 16) {
        if (t < 64) {
            int r = t >> 2, ja = (t & 3) << 2;
            float4 a = *(const float4*)(q + (size_t)(rowbase + r)*NC + c0 + ja);
            qqT[ja+0][r] = a.x; qqT[ja+1][r] = a.y; qqT[ja+2][r] = a.z; qqT[ja+3][r] = a.w;
        }
        #pragma unroll
        for (int it2 = 0; it2 < 8; ++it2) {
            int id = it2*256 + t;
            int p = id >> 2, ja = (id & 3) << 2;
            float4 a = *(const float4*)(kb + (size_t)p*NC + c0 + ja);
            kkT[ja+0][p] = a.x; kkT[ja+1][p] = a.y; kkT[ja+2][p] = a.z; kkT[ja+3][p] = a.w;
        }
        __syncthreads();
        #pragma unroll
        for (int jj = 0; jj < 16; ++jj) {
            float4 kv = *(const float4*)&kkT[jj][pg<<2];
            float4 qa = *(const float4*)&qqT[jj][rg<<3];
            float4 qb = *(const float4*)&qqT[jj][(rg<<3)+4];
            float qv[8] = {qa.x,qa.y,qa.z,qa.w,qb.x,qb.y,qb.z,qb.w};
            float kk4[4] = {kv.x,kv.y,kv.z,kv.w};
            #pragma unroll
            for (int rr = 0; rr < 8; ++rr)
                #pragma unroll
                for (int cc = 0; cc < 4; ++cc)
                    acc[rr][cc] += qv[rr]*kk4[cc];
        }
        __syncthreads();
    }
    float mk[4];
    #pragma unroll
    for (int cc = 0; cc < 4; ++cc) mk[cc] = (maskp[b*NK + (pg<<2) + cc] - 1.0f)*1e9f;
    #pragma unroll
    for (int rr = 0; rr < 8; ++rr) {
        float bv = -INFINITY; int bj = 0;
        #pragma unroll
        for (int cc = 0; cc < 4; ++cc) {
            float v = acc[rr][cc]*INV_SQRT_C + mk[cc];
            if (v > bv) { bv = v; bj = cc; }
        }
        sv[(rg<<3)+rr][pg] = bv;
        si[(rg<<3)+rr][pg] = (pg<<2) + bj;
    }
    __syncthreads();
    if (t < 16) {
        float bv = -INFINITY; int bi = 0;
        for (int x = 0; x < 128; ++x) {        // ascending parent blocks: first-max kept
            float v = sv[t][x];
            if (v > bv) { bv = v; bi = si[t][x]; }
        }
        j0[rowbase + t] = bi;
    }
}

// ---------------- kernel 6: gathered attention epilogue ----------------
__global__ __launch_bounds__(256) void k_final(const float* __restrict__ q,
                                               const float* __restrict__ kmat,
                                               const float* __restrict__ vmat,
                                               const float* __restrict__ mu,
                                               const float* __restrict__ Sg,
                                               const float* __restrict__ node_mask,
                                               const int* __restrict__ j0,
                                               const int* __restrict__ knn,
                                               float* __restrict__ out_s0,
                                               float* __restrict__ out_mu0,
                                               float* __restrict__ out_Sig0,
                                               float* __restrict__ out_Bl,
                                               float* __restrict__ occ,
                                               float* __restrict__ loss_part) {
    int row = blockIdx.x, t = threadIdx.x;
    int b = row >> 12;
    __shared__ int   pidx[NR];
    __shared__ float lg[NR];
    __shared__ float wl[NR];
    float m = node_mask[row];
    if (t < NR) pidx[t] = knn[((size_t)(b*NK + j0[row]))*NR + t];
    __syncthreads();
    // logits over the 16 gathered parents: 16 groups x 16 lanes
    int g = t >> 4, l = t & 15;
    const float* qr = q + (size_t)row*NC;
    const float* kr = kmat + (size_t)(b*NK + pidx[g])*NC;
    float s = 0.f;
    for (int c = l; c < NC; c += 16) s += qr[c]*kr[c];
    #pragma unroll
    for (int off = 8; off > 0; off >>= 1) s += __shfl_xor(s, off);
    if (l == 0) lg[g] = s*INV_SQRT_C + (m-1.0f)*1e9f;
    __syncthreads();
    if (t < NR) {   // softmax over 16 (lanes 0..15 of wave 0)
        float v = lg[t];
        float mx = v;
        #pragma unroll
        for (int off = 8; off > 0; off >>= 1) mx = fmaxf(mx, __shfl_xor(mx, off));
        float e = expf(v - mx);
        float sme = e;
        #pragma unroll
        for (int off = 8; off > 0; off >>= 1) sme += __shfl_xor(sme, off);
        float w = e/sme;
        wl[t] = w;
        out_Bl[(size_t)row*NR + t] = w;
    }
    __syncthreads();
    const float* vb = vmat + (size_t)b*NK*NC;
    for (int c = t; c < NC; c += 256) {
        float a = 0.f;
        #pragma unroll
        for (int r2 = 0; r2 < NR; ++r2) a += wl[r2]*vb[(size_t)pidx[r2]*NC + c];
        out_s0[(size_t)row*NC + c] = a*m;
    }
    if (t < NR) {
        const float* mur = mu + (size_t)(b*NK + pidx[t])*3;
        const float* Sgr = Sg + (size_t)(b*NK + pidx[t])*9;
        float w = wl[t];
        float mr0 = mur[0], mr1 = mur[1], mr2 = mur[2];
        float m0 = w*mr0, m1 = w*mr1, m2 = w*mr2;
        #pragma unroll
        for (int off = 8; off > 0; off >>= 1) {
            m0 += __shfl_xor(m0, off); m1 += __shfl_xor(m1, off); m2 += __shfl_xor(m2, off);
        }
        float d0 = mr0-m0, d1 = mr1-m1, d2 = mr2-m2;   // mu_sub - mu0 (sign cancels in maha)
        float a00 = Sgr[0], a01 = Sgr[1], a02 = Sgr[2];
        float a11 = Sgr[4], a12 = Sgr[5], a22 = Sgr[8];
        float p00 = w*(a00 + d0*d0), p01 = w*(a01 + d0*d1), p02 = w*(a02 + d0*d2);
        float p11 = w*(a11 + d1*d1), p12 = w*(a12 + d1*d2), p22 = w*(a22 + d2*d2);
        #pragma unroll
        for (int off = 8; off > 0; off >>= 1) {
            p00 += __shfl_xor(p00, off); p01 += __shfl_xor(p01, off); p02 += __shfl_xor(p02, off);
            p11 += __shfl_xor(p11, off); p12 += __shfl_xor(p12, off); p22 += __shfl_xor(p22, off);
        }
        // overlap score on raw Sig_sub
        float c00 = a11*a22 - a12*a12;
        float c01 = a02*a12 - a01*a22;
        float c02 = a01*a12 - a02*a11;
        float c11 = a00*a22 - a02*a02;
        float c12 = a01*a02 - a00*a12;
        float c22 = a00*a11 - a01*a01;
        float det = a00*c00 + a01*c01 + a02*c02;
        float t0 = c00*d0 + c01*d1 + c02*d2;
        float t1 = c01*d0 + c11*d1 + c12*d2;
        float t2 = c02*d0 + c12*d1 + c22*d2;
        float maha = (d0*t0 + d1*t1 + d2*t2) / det;
        float score = -0.5f*(maha + logf(det));
        float lp = w*score;
        #pragma unroll
        for (int off = 8; off > 0; off >>= 1) lp += __shfl_xor(lp, off);
        if (t == 0) {
            out_mu0[(size_t)row*3+0] = m0;
            out_mu0[(size_t)row*3+1] = m1;
            out_mu0[(size_t)row*3+2] = m2;
            float* o = out_Sig0 + (size_t)row*9;
            o[0]=p00+F_JITTER; o[1]=p01;          o[2]=p02;
            o[3]=p01;          o[4]=p11+F_JITTER; o[5]=p12;
            o[6]=p02;          o[7]=p12;          o[8]=p22+F_JITTER;
            atomicAdd(&loss_part[row & 255], m*lp);
        }
        atomicAdd(&occ[b*NK + pidx[t]], w*m);
    }
}

// ---------------- kernel 7: occ normalize + loss ----------------
__global__ __launch_bounds__(256) void k_finalize(const float* __restrict__ occ,
                                                  const float* __restrict__ Lsum,
                                                  const float* __restrict__ loss_part,
                                                  float* __restrict__ out_occn,
                                                  float* __restrict__ out_loss) {
    int t = threadIdx.x;
    __shared__ float red[256];
    red[t] = loss_part[t];
    __syncthreads();
    for (int w = 128; w > 0; w >>= 1) { if (t < w) red[t] += red[t+w]; __syncthreads(); }
    float lsum = red[0];
    __syncthreads();
    for (int b = 0; b < NB; ++b) {
        float o0 = occ[b*NK + t], o1 = occ[b*NK + 256 + t];
        red[t] = o0 + o1;
        __syncthreads();
        for (int w = 128; w > 0; w >>= 1) { if (t < w) red[t] += red[t+w]; __syncthreads(); }
        float inv = 1.0f / fmaxf(red[0], 1e-9f);
        __syncthreads();
        out_occn[b*NK + t]       = o0*inv;
        out_occn[b*NK + 256 + t] = o1*inv;
    }
    if (t == 0) {
        float dnm = fmaxf(Lsum[0] + Lsum[1], 1.0f);
        out_loss[0] = -(lsum / dnm);   // W_ATTACH=1, W_ENTB=0
    }
}

extern "C" void kernel_launch(void* const* d_in, const int* in_sizes, int n_in,
                              void* d_out, int out_size, void* d_ws, size_t ws_size,
                              hipStream_t stream) {
    const float* s_parent   = (const float*)d_in[0];
    const float* mu_parent  = (const float*)d_in[1];
    const float* Sig_parent = (const float*)d_in[2];
    const float* mask_par   = (const float*)d_in[3];
    const float* node_mask  = (const float*)d_in[4];
    const int*   res_idx    = (const int*)d_in[5];
    const float* Bm         = (const float*)d_in[6];
    const float* Wq         = (const float*)d_in[7];
    const float* Wk         = (const float*)d_in[8];
    const float* Wv         = (const float*)d_in[9];
    const float* ln_g       = (const float*)d_in[10];
    const float* ln_b       = (const float*)d_in[11];

    float* ws = (float*)d_ws;
    const size_t OFF_Q0  = 0;
    const size_t OFF_Q   = OFF_Q0  + (size_t)NB*NN*NC;     // 3145728
    const size_t OFF_K   = OFF_Q   + (size_t)NB*NN*NC;     // 6291456
    const size_t OFF_V   = OFF_K   + (size_t)NB*NK*NC;     // 6684672
    const size_t OFF_J0  = OFF_V   + (size_t)NB*NK*NC;     // 7077888 (ints)
    const size_t OFF_KNN = OFF_J0  + (size_t)NB*NN;        // 7086080 (ints)
    const size_t OFF_LS  = OFF_KNN + (size_t)NB*NK*NR;     // 7102464
    const size_t OFF_LP  = OFF_LS  + 16;                   // 7102480
    const size_t OFF_OCC = OFF_LP  + 256;                  // 7102736
    float* q0    = ws + OFF_Q0;
    float* q     = ws + OFF_Q;
    float* kmat  = ws + OFF_K;
    float* vmat  = ws + OFF_V;
    int*   j0    = (int*)(ws + OFF_J0);
    int*   knn   = (int*)(ws + OFF_KNN);
    float* Lsum  = ws + OFF_LS;
    float* lpart = ws + OFF_LP;
    float* occ   = ws + OFF_OCC;

    float* out      = (float*)d_out;
    float* out_s0   = out;
    float* out_mu0  = out      + (size_t)NB*NN*NC;
    float* out_Sig0 = out_mu0  + (size_t)NB*NN*3;
    float* out_Bl   = out_Sig0 + (size_t)NB*NN*9;
    float* out_occn = out_Bl   + (size_t)NB*NN*NR;
    float* out_loss = out_occn + (size_t)NB*NK;

    (void)in_sizes; (void)n_in; (void)out_size; (void)ws_size;

    hipMemsetAsync(lpart, 0, (256 + NB*NK)*sizeof(float), stream);
    k_masksum<<<NB, 256, 0, stream>>>(node_mask, Lsum);
    k_q0<<<NB*NN, 128, 0, stream>>>(res_idx, node_mask, Bm, ln_g, ln_b, Lsum, q0);
    k_gemm384<<<dim3((NB*NN)/64, NC/64), 256, 0, stream>>>(q0, Wq, q);
    k_gemm384<<<dim3((NB*NK)/64, NC/64), 256, 0, stream>>>(s_parent, Wk, kmat);
    k_gemm384<<<dim3((NB*NK)/64, NC/64), 256, 0, stream>>>(s_parent, Wv, vmat);
    k_score_topk<<<NB*NK, 256, 0, stream>>>(mu_parent, Sig_parent, mask_par, knn);
    k_logits_argmax<<<(NB*NN)/16, 256, 0, stream>>>(q, kmat, mask_par, j0);
    k_final<<<NB*NN, 256, 0, stream>>>(q, kmat, vmat, mu_parent, Sig_parent, node_mask,
                                       j0, knn, out_s0, out_mu0, out_Sig0, out_Bl, occ, lpart);
    k_finalize<<<1, 256, 0, stream>>>(occ, Lsum, lpart, out_occn, out_loss);
}

// Round 2
// 303.744 us; speedup vs baseline: 1.1251x; 1.1251x over previous
//
#include <hip/hip_runtime.h>
#include <math.h>

#define NB 2
#define NN 4096
#define NK 512
#define NC 384
#define NR 16
#define NCH 192

static constexpr float INV_SQRT_C = 0.051031036307982884f; // 1/sqrt(384)
static constexpr float TWO_PI     = 6.283185307179586f;
static constexpr float F_JITTER   = 1e-4f;

// ---------------- kernel 1: per-batch node_mask sum ----------------
__global__ __launch_bounds__(256) void k_masksum(const float* __restrict__ node_mask,
                                                 float* __restrict__ Lsum) {
    int b = blockIdx.x, t = threadIdx.x;
    __shared__ float red[256];
    float s = 0.f;
    for (int n = t; n < NN; n += 256) s += node_mask[b*NN + n];
    red[t] = s; __syncthreads();
    for (int w = 128; w > 0; w >>= 1) { if (t < w) red[t] += red[t+w]; __syncthreads(); }
    if (t == 0) Lsum[b] = red[0];
}

// ---------------- kernel 2: fourier emb + layernorm -> q0 ----------------
__global__ __launch_bounds__(128) void k_q0(const int* __restrict__ res_idx,
                                            const float* __restrict__ node_mask,
                                            const float* __restrict__ Bm,
                                            const float* __restrict__ ln_g,
                                            const float* __restrict__ ln_b,
                                            const float* __restrict__ Lsum,
                                            float* __restrict__ q0) {
    int row = blockIdx.x, t = threadIdx.x;
    int b = row >> 12;
    __shared__ float emb[NC];
    __shared__ float red[128];
    float m = node_mask[row];
    float Lb = fmaxf(Lsum[b], 1.0f);
    float denom = fmaxf(Lb - 1.0f, 1.0f);
    int ri = res_idx[row];
    ri = ri < 0 ? 0 : (ri > 4095 ? 4095 : ri);
    float pos = fminf(fmaxf((float)ri / denom, 0.f), 1.f);
    for (int i = t; i < NCH; i += 128) {
        float pr = TWO_PI * pos * Bm[i];
        emb[i]      = cosf(pr) * m;
        emb[i+NCH]  = sinf(pr) * m;
    }
    __syncthreads();
    float e0 = emb[t], e1 = emb[t+128], e2 = emb[t+256];
    red[t] = e0 + e1 + e2; __syncthreads();
    for (int w = 64; w > 0; w >>= 1) { if (t < w) red[t] += red[t+w]; __syncthreads(); }
    float mean = red[0] * (1.0f/NC);
    __syncthreads();
    float d0 = e0-mean, d1 = e1-mean, d2 = e2-mean;
    red[t] = d0*d0 + d1*d1 + d2*d2; __syncthreads();
    for (int w = 64; w > 0; w >>= 1) { if (t < w) red[t] += red[t+w]; __syncthreads(); }
    float var = red[0] * (1.0f/NC);
    float inv = 1.0f / sqrtf(var + 1e-5f);
    q0[(size_t)row*NC + t]       = d0*inv*ln_g[t]      + ln_b[t];
    q0[(size_t)row*NC + t + 128] = d1*inv*ln_g[t+128]  + ln_b[t+128];
    q0[(size_t)row*NC + t + 256] = d2*inv*ln_g[t+256]  + ln_b[t+256];
}

// ---------------- kernel 3: generic [M,384]@[384,384] fp32 GEMM ----------------
__global__ __launch_bounds__(256) void k_gemm384(const float* __restrict__ A,
                                                 const float* __restrict__ W,
                                                 float* __restrict__ out) {
    __shared__ float As[16][68];
    __shared__ float Ws[16][68];
    int t = threadIdx.x;
    int tx = t & 15, ty = t >> 4;
    int rowbase = blockIdx.x * 64, colbase = blockIdx.y * 64;
    float acc[4][4] = {};
    for (int k0 = 0; k0 < NC; k0 += 16) {
        {
            int r = t >> 2, ja = (t & 3) << 2;
            float4 a4 = *(const float4*)(A + (size_t)(rowbase + r)*NC + k0 + ja);
            As[ja+0][r] = a4.x; As[ja+1][r] = a4.y; As[ja+2][r] = a4.z; As[ja+3][r] = a4.w;
        }
        {
            int kr = t >> 4, jw = (t & 15) << 2;
            float4 w4 = *(const float4*)(W + (size_t)(k0 + kr)*NC + colbase + jw);
            *(float4*)&Ws[kr][jw] = w4;
        }
        __syncthreads();
        #pragma unroll
        for (int kk = 0; kk < 16; ++kk) {
            float4 av = *(const float4*)&As[kk][ty<<2];
            float4 wv = *(const float4*)&Ws[kk][tx<<2];
            float aa[4] = {av.x, av.y, av.z, av.w};
            float ww[4] = {wv.x, wv.y, wv.z, wv.w};
            #pragma unroll
            for (int i = 0; i < 4; ++i)
                #pragma unroll
                for (int j = 0; j < 4; ++j)
                    acc[i][j] += aa[i]*ww[j];
        }
        __syncthreads();
    }
    #pragma unroll
    for (int i = 0; i < 4; ++i) {
        float4 o = make_float4(acc[i][0], acc[i][1], acc[i][2], acc[i][3]);
        *(float4*)(out + (size_t)(rowbase + (ty<<2) + i)*NC + colbase + (tx<<2)) = o;
    }
}

// ---------------- kernel 4: K x K overlap scores + top-16 per row ----------------
// register-held candidates + wave shuffle reduction (2 barriers/iter)
__global__ __launch_bounds__(256) void k_score_topk(const float* __restrict__ mu,
                                                    const float* __restrict__ Sg,
                                                    const float* __restrict__ maskp,
                                                    int* __restrict__ knn) {
    int b = blockIdx.x >> 9, i = blockIdx.x & 511;
    int t = threadIdx.x;
    __shared__ float swv[4];
    __shared__ int   swi[4];
    __shared__ int   winner;
    const float* mui = mu + (size_t)(b*NK + i)*3;
    const float* Sgi = Sg + (size_t)(b*NK + i)*9;
    float mi0 = mui[0], mi1 = mui[1], mi2 = mui[2];
    float S0 = Sgi[0], S1 = Sgi[1], S2 = Sgi[2], S4 = Sgi[4], S5 = Sgi[5], S8 = Sgi[8];
    float mski = maskp[b*NK + i];
    float cand[2];
    #pragma unroll
    for (int h = 0; h < 2; ++h) {
        int j = t + h*256;
        const float* muj = mu + (size_t)(b*NK + j)*3;
        const float* Sgj = Sg + (size_t)(b*NK + j)*9;
        float d0 = mi0-muj[0], d1 = mi1-muj[1], d2 = mi2-muj[2];
        float a00 = S0+Sgj[0]+1e-6f, a01 = S1+Sgj[1],       a02 = S2+Sgj[2];
        float a11 = S4+Sgj[4]+1e-6f, a12 = S5+Sgj[5],       a22 = S8+Sgj[8]+1e-6f;
        float c00 = a11*a22 - a12*a12;
        float c01 = a02*a12 - a01*a22;
        float c02 = a01*a12 - a02*a11;
        float c11 = a00*a22 - a02*a02;
        float c12 = a01*a02 - a00*a12;
        float c22 = a00*a11 - a01*a01;
        float det = a00*c00 + a01*c01 + a02*c02;
        float t0 = c00*d0 + c01*d1 + c02*d2;
        float t1 = c01*d0 + c11*d1 + c12*d2;
        float t2 = c02*d0 + c12*d1 + c22*d2;
        float maha = (d0*t0 + d1*t1 + d2*t2) / det;
        float score = -0.5f*(maha + logf(det));
        float mj = maskp[b*NK + j];
        cand[h] = (mski*mj < 0.5f) ? -1e9f : score;
    }
    int lane = t & 63, wv = t >> 6;
    for (int it = 0; it < NR; ++it) {
        float bv; int bi;
        if (cand[0] >= cand[1]) { bv = cand[0]; bi = t; }       // >= keeps smaller index on tie
        else                    { bv = cand[1]; bi = t + 256; }
        #pragma unroll
        for (int off = 32; off > 0; off >>= 1) {
            float v2 = __shfl_xor(bv, off);
            int   i2 = __shfl_xor(bi, off);
            if (v2 > bv || (v2 == bv && i2 < bi)) { bv = v2; bi = i2; }
        }
        if (lane == 0) { swv[wv] = bv; swi[wv] = bi; }
        __syncthreads();
        if (t == 0) {
            float B = swv[0]; int I = swi[0];
            #pragma unroll
            for (int w = 1; w < 4; ++w)
                if (swv[w] > B || (swv[w] == B && swi[w] < I)) { B = swv[w]; I = swi[w]; }
            knn[((size_t)(b*NK + i))*NR + it] = I;
            winner = I;
        }
        __syncthreads();
        int wn = winner;
        if (t == wn)        cand[0] = -INFINITY;
        if (t + 256 == wn)  cand[1] = -INFINITY;
    }
}

// ---------------- kernel 5: logits_full + argmax + store raw scaled logits ----------------
__global__ __launch_bounds__(256) void k_logits_argmax(const float* __restrict__ q,
                                                       const float* __restrict__ kmat,
                                                       const float* __restrict__ maskp,
                                                       int* __restrict__ j0,
                                                       float* __restrict__ lg_out) {
    int t = threadIdx.x;
    int rowbase = blockIdx.x << 4;
    int b = rowbase >> 12;
    __shared__ float kkT[16][NK];      // [c][p] transposed k chunk
    __shared__ float qqT[16][20];      // [c][row]
    __shared__ float sv[16][128];
    __shared__ int   si[16][128];
    int pg = t & 127, rg = t >> 7;     // 4 parents x 8 rows per thread
    float acc[8][4] = {};
    const float* kb = kmat + (size_t)b*NK*NC;
    for (int c0 = 0; c0 < NC; c0 += 16) {
        if (t < 64) {
            int r = t >> 2, ja = (t & 3) << 2;
            float4 a = *(const float4*)(q + (size_t)(rowbase + r)*NC + c0 + ja);
            qqT[ja+0][r] = a.x; qqT[ja+1][r] = a.y; qqT[ja+2][r] = a.z; qqT[ja+3][r] = a.w;
        }
        #pragma unroll
        for (int it2 = 0; it2 < 8; ++it2) {
            int id = it2*256 + t;
            int p = id >> 2, ja = (id & 3) << 2;
            float4 a = *(const float4*)(kb + (size_t)p*NC + c0 + ja);
            kkT[ja+0][p] = a.x; kkT[ja+1][p] = a.y; kkT[ja+2][p] = a.z; kkT[ja+3][p] = a.w;
        }
        __syncthreads();
        #pragma unroll
        for (int jj = 0; jj < 16; ++jj) {
            float4 kv = *(const float4*)&kkT[jj][pg<<2];
            float4 qa = *(const float4*)&qqT[jj][rg<<3];
            float4 qb = *(const float4*)&qqT[jj][(rg<<3)+4];
            float qv[8] = {qa.x,qa.y,qa.z,qa.w,qb.x,qb.y,qb.z,qb.w};
            float kk4[4] = {kv.x,kv.y,kv.z,kv.w};
            #pragma unroll
            for (int rr = 0; rr < 8; ++rr)
                #pragma unroll
                for (int cc = 0; cc < 4; ++cc)
                    acc[rr][cc] += qv[rr]*kk4[cc];
        }
        __syncthreads();
    }
    float mk[4];
    #pragma unroll
    for (int cc = 0; cc < 4; ++cc) mk[cc] = (maskp[b*NK + (pg<<2) + cc] - 1.0f)*1e9f;
    #pragma unroll
    for (int rr = 0; rr < 8; ++rr) {
        int rloc = (rg<<3) + rr;
        float raw[4];
        float bv = -INFINITY; int bj = 0;
        #pragma unroll
        for (int cc = 0; cc < 4; ++cc) {
            raw[cc] = acc[rr][cc]*INV_SQRT_C;
            float v = raw[cc] + mk[cc];
            if (v > bv) { bv = v; bj = cc; }
        }
        *(float4*)(lg_out + (size_t)(rowbase + rloc)*NK + (pg<<2)) =
            make_float4(raw[0], raw[1], raw[2], raw[3]);
        sv[rloc][pg] = bv;
        si[rloc][pg] = (pg<<2) + bj;
    }
    __syncthreads();
    if (t < 16) {
        float bv = -INFINITY; int bi = 0;
        for (int x = 0; x < 128; ++x) {        // ascending parent blocks: first-max kept
            float v = sv[t][x];
            if (v > bv) { bv = v; bi = si[t][x]; }
        }
        j0[rowbase + t] = bi;
    }
}

// ---------------- kernel 6: gathered attention epilogue (logits precomputed) ----------------
__global__ __launch_bounds__(256) void k_final(const float* __restrict__ logits,
                                               const float* __restrict__ vmat,
                                               const float* __restrict__ mu,
                                               const float* __restrict__ Sg,
                                               const float* __restrict__ node_mask,
                                               const int* __restrict__ j0,
                                               const int* __restrict__ knn,
                                               float* __restrict__ out_s0,
                                               float* __restrict__ out_mu0,
                                               float* __restrict__ out_Sig0,
                                               float* __restrict__ out_Bl,
                                               float* __restrict__ occ,
                                               float* __restrict__ loss_part) {
    int row = blockIdx.x, t = threadIdx.x;
    int b = row >> 12;
    __shared__ int    pidx[NR];
    __shared__ float  wl[NR];
    __shared__ float4 part[96];
    float m = node_mask[row];
    if (t < NR) {
        int p = knn[((size_t)(b*NK + j0[row]))*NR + t];
        pidx[t] = p;
        // softmax over 16 lanes of wave 0 (node-mask shift is uniform -> softmax-invariant)
        float v = logits[(size_t)row*NK + p];
        float mx = v;
        #pragma unroll
        for (int off = 8; off > 0; off >>= 1) mx = fmaxf(mx, __shfl_xor(mx, off));
        float e = expf(v - mx);
        float sme = e;
        #pragma unroll
        for (int off = 8; off > 0; off >>= 1) sme += __shfl_xor(sme, off);
        float w = e/sme;
        wl[t] = w;
        out_Bl[(size_t)row*NR + t] = w;

        // mu0 / Sig0 / attach score — all within lanes 0..15
        const float* mur = mu + (size_t)(b*NK + p)*3;
        const float* Sgr = Sg + (size_t)(b*NK + p)*9;
        float mr0 = mur[0], mr1 = mur[1], mr2 = mur[2];
        float m0 = w*mr0, m1 = w*mr1, m2 = w*mr2;
        #pragma unroll
        for (int off = 8; off > 0; off >>= 1) {
            m0 += __shfl_xor(m0, off); m1 += __shfl_xor(m1, off); m2 += __shfl_xor(m2, off);
        }
        float d0 = mr0-m0, d1 = mr1-m1, d2 = mr2-m2;   // mu_sub - mu0 (sign cancels in maha)
        float a00 = Sgr[0], a01 = Sgr[1], a02 = Sgr[2];
        float a11 = Sgr[4], a12 = Sgr[5], a22 = Sgr[8];
        float p00 = w*(a00 + d0*d0), p01 = w*(a01 + d0*d1), p02 = w*(a02 + d0*d2);
        float p11 = w*(a11 + d1*d1), p12 = w*(a12 + d1*d2), p22 = w*(a22 + d2*d2);
        #pragma unroll
        for (int off = 8; off > 0; off >>= 1) {
            p00 += __shfl_xor(p00, off); p01 += __shfl_xor(p01, off); p02 += __shfl_xor(p02, off);
            p11 += __shfl_xor(p11, off); p12 += __shfl_xor(p12, off); p22 += __shfl_xor(p22, off);
        }
        float c00 = a11*a22 - a12*a12;
        float c01 = a02*a12 - a01*a22;
        float c02 = a01*a12 - a02*a11;
        float c11 = a00*a22 - a02*a02;
        float c12 = a01*a02 - a00*a12;
        float c22 = a00*a11 - a01*a01;
        float det = a00*c00 + a01*c01 + a02*c02;
        float t0 = c00*d0 + c01*d1 + c02*d2;
        float t1 = c01*d0 + c11*d1 + c12*d2;
        float t2 = c02*d0 + c12*d1 + c22*d2;
        float maha = (d0*t0 + d1*t1 + d2*t2) / det;
        float score = -0.5f*(maha + logf(det));
        float lp = w*score;
        #pragma unroll
        for (int off = 8; off > 0; off >>= 1) lp += __shfl_xor(lp, off);
        if (t == 0) {
            out_mu0[(size_t)row*3+0] = m0;
            out_mu0[(size_t)row*3+1] = m1;
            out_mu0[(size_t)row*3+2] = m2;
            float* o = out_Sig0 + (size_t)row*9;
            o[0]=p00+F_JITTER; o[1]=p01;          o[2]=p02;
            o[3]=p01;          o[4]=p11+F_JITTER; o[5]=p12;
            o[6]=p02;          o[7]=p12;          o[8]=p22+F_JITTER;
            atomicAdd(&loss_part[row & 255], m*lp);
        }
        atomicAdd(&occ[b*NK + p], w*m);
    }
    __syncthreads();
    // s0: float4-vectorized weighted sum of 16 gathered V rows
    int g = t >> 7, c4 = t & 127;
    const float4* vb = (const float4*)(vmat + (size_t)b*NK*NC);
    if (c4 < 96) {
        float4 a = make_float4(0.f, 0.f, 0.f, 0.f);
        #pragma unroll
        for (int r2 = 0; r2 < 8; ++r2) {
            int r = (g<<3) + r2;
            float w = wl[r];
            float4 vv = vb[(size_t)pidx[r]*96 + c4];
            a.x += w*vv.x; a.y += w*vv.y; a.z += w*vv.z; a.w += w*vv.w;
        }
        if (g == 0) part[c4] = a;
    }
    __syncthreads();
    if (g == 1 && c4 < 96) {
        float4 p0 = part[c4];
        float4 a;
        a.x = 0.f; a.y = 0.f; a.z = 0.f; a.w = 0.f;
        // recompute local a was stored in regs above; rebuild from scratch is wrong —
        // instead keep it: (we still have `a` in scope only inside the if above)
        // so redo the accumulation here for g==1:
        #pragma unroll
        for (int r2 = 8; r2 < 16; ++r2) {
            float w = wl[r2];
            float4 vv = vb[(size_t)pidx[r2]*96 + c4];
            a.x += w*vv.x; a.y += w*vv.y; a.z += w*vv.z; a.w += w*vv.w;
        }
        a.x = (a.x + p0.x)*m; a.y = (a.y + p0.y)*m;
        a.z = (a.z + p0.z)*m; a.w = (a.w + p0.w)*m;
        ((float4*)(out_s0 + (size_t)row*NC))[c4] = a;
    }
}

// ---------------- kernel 7: occ normalize + loss ----------------
__global__ __launch_bounds__(256) void k_finalize(const float* __restrict__ occ,
                                                  const float* __restrict__ Lsum,
                                                  const float* __restrict__ loss_part,
                                                  float* __restrict__ out_occn,
                                                  float* __restrict__ out_loss) {
    int t = threadIdx.x;
    __shared__ float red[256];
    red[t] = loss_part[t];
    __syncthreads();
    for (int w = 128; w > 0; w >>= 1) { if (t < w) red[t] += red[t+w]; __syncthreads(); }
    float lsum = red[0];
    __syncthreads();
    for (int b = 0; b < NB; ++b) {
        float o0 = occ[b*NK + t], o1 = occ[b*NK + 256 + t];
        red[t] = o0 + o1;
        __syncthreads();
        for (int w = 128; w > 0; w >>= 1) { if (t < w) red[t] += red[t+w]; __syncthreads(); }
        float inv = 1.0f / fmaxf(red[0], 1e-9f);
        __syncthreads();
        out_occn[b*NK + t]       = o0*inv;
        out_occn[b*NK + 256 + t] = o1*inv;
    }
    if (t == 0) {
        float dnm = fmaxf(Lsum[0] + Lsum[1], 1.0f);
        out_loss[0] = -(lsum / dnm);   // W_ATTACH=1, W_ENTB=0
    }
}

extern "C" void kernel_launch(void* const* d_in, const int* in_sizes, int n_in,
                              void* d_out, int out_size, void* d_ws, size_t ws_size,
                              hipStream_t stream) {
    const float* s_parent   = (const float*)d_in[0];
    const float* mu_parent  = (const float*)d_in[1];
    const float* Sig_parent = (const float*)d_in[2];
    const float* mask_par   = (const float*)d_in[3];
    const float* node_mask  = (const float*)d_in[4];
    const int*   res_idx    = (const int*)d_in[5];
    const float* Bm         = (const float*)d_in[6];
    const float* Wq         = (const float*)d_in[7];
    const float* Wk         = (const float*)d_in[8];
    const float* Wv         = (const float*)d_in[9];
    const float* ln_g       = (const float*)d_in[10];
    const float* ln_b       = (const float*)d_in[11];

    float* ws = (float*)d_ws;
    // region A is shared: q0 (alive: k_q0 -> gemm) then logits (alive: k_logits_argmax -> k_final)
    const size_t OFF_A   = 0;                               // max(3145728, 4194304)
    const size_t OFF_Q   = OFF_A   + (size_t)NB*NN*NK;      // 4194304
    const size_t OFF_K   = OFF_Q   + (size_t)NB*NN*NC;      // +3145728
    const size_t OFF_V   = OFF_K   + (size_t)NB*NK*NC;      // +393216
    const size_t OFF_J0  = OFF_V   + (size_t)NB*NK*NC;      // +393216 (ints)
    const size_t OFF_KNN = OFF_J0  + (size_t)NB*NN;         // +8192 (ints)
    const size_t OFF_LS  = OFF_KNN + (size_t)NB*NK*NR;      // +16384
    const size_t OFF_LP  = OFF_LS  + 16;
    const size_t OFF_OCC = OFF_LP  + 256;
    float* q0     = ws + OFF_A;
    float* logits = ws + OFF_A;
    float* q      = ws + OFF_Q;
    float* kmat   = ws + OFF_K;
    float* vmat   = ws + OFF_V;
    int*   j0     = (int*)(ws + OFF_J0);
    int*   knn    = (int*)(ws + OFF_KNN);
    float* Lsum   = ws + OFF_LS;
    float* lpart  = ws + OFF_LP;
    float* occ    = ws + OFF_OCC;

    float* out      = (float*)d_out;
    float* out_s0   = out;
    float* out_mu0  = out      + (size_t)NB*NN*NC;
    float* out_Sig0 = out_mu0  + (size_t)NB*NN*3;
    float* out_Bl   = out_Sig0 + (size_t)NB*NN*9;
    float* out_occn = out_Bl   + (size_t)NB*NN*NR;
    float* out_loss = out_occn + (size_t)NB*NK;

    (void)in_sizes; (void)n_in; (void)out_size; (void)ws_size;

    hipMemsetAsync(lpart, 0, (256 + NB*NK)*sizeof(float), stream);
    k_masksum<<<NB, 256, 0, stream>>>(node_mask, Lsum);
    k_q0<<<NB*NN, 128, 0, stream>>>(res_idx, node_mask, Bm, ln_g, ln_b, Lsum, q0);
    k_gemm384<<<dim3((NB*NN)/64, NC/64), 256, 0, stream>>>(q0, Wq, q);
    k_gemm384<<<dim3((NB*NK)/64, NC/64), 256, 0, stream>>>(s_parent, Wk, kmat);
    k_gemm384<<<dim3((NB*NK)/64, NC/64), 256, 0, stream>>>(s_parent, Wv, vmat);
    k_score_topk<<<NB*NK, 256, 0, stream>>>(mu_parent, Sig_parent, mask_par, knn);
    k_logits_argmax<<<(NB*NN)/16, 256, 0, stream>>>(q, kmat, mask_par, j0, logits);
    k_final<<<NB*NN, 256, 0, stream>>>(logits, vmat, mu_parent, Sig_parent, node_mask,
                                       j0, knn, out_s0, out_mu0, out_Sig0, out_Bl, occ, lpart);
    k_finalize<<<1, 256, 0, stream>>>(occ, Lsum, lpart, out_occn, out_loss);
}

// Round 3
// 216.168 us; speedup vs baseline: 1.5809x; 1.4051x over previous
//
#include <hip/hip_runtime.h>
#include <math.h>

#define NB 2
#define NN 4096
#define NK 512
#define NC 384
#define NR 16
#define NCH 192
#define NSLICE 64

static constexpr float INV_SQRT_C = 0.051031036307982884f; // 1/sqrt(384)
static constexpr float TWO_PI     = 6.283185307179586f;
static constexpr float F_JITTER   = 1e-4f;

// ---------------- kernel 1: per-batch node_mask sum ----------------
__global__ __launch_bounds__(256) void k_masksum(const float* __restrict__ node_mask,
                                                 float* __restrict__ Lsum) {
    int b = blockIdx.x, t = threadIdx.x;
    __shared__ float red[256];
    float s = 0.f;
    for (int n = t; n < NN; n += 256) s += node_mask[b*NN + n];
    red[t] = s; __syncthreads();
    for (int w = 128; w > 0; w >>= 1) { if (t < w) red[t] += red[t+w]; __syncthreads(); }
    if (t == 0) Lsum[b] = red[0];
}

// ---------------- kernel 2: fourier emb + layernorm -> q0 ----------------
__global__ __launch_bounds__(128) void k_q0(const int* __restrict__ res_idx,
                                            const float* __restrict__ node_mask,
                                            const float* __restrict__ Bm,
                                            const float* __restrict__ ln_g,
                                            const float* __restrict__ ln_b,
                                            const float* __restrict__ Lsum,
                                            float* __restrict__ q0) {
    int row = blockIdx.x, t = threadIdx.x;
    int b = row >> 12;
    __shared__ float emb[NC];
    __shared__ float red[128];
    float m = node_mask[row];
    float Lb = fmaxf(Lsum[b], 1.0f);
    float denom = fmaxf(Lb - 1.0f, 1.0f);
    int ri = res_idx[row];
    ri = ri < 0 ? 0 : (ri > 4095 ? 4095 : ri);
    float pos = fminf(fmaxf((float)ri / denom, 0.f), 1.f);
    for (int i = t; i < NCH; i += 128) {
        float pr = TWO_PI * pos * Bm[i];
        emb[i]      = cosf(pr) * m;
        emb[i+NCH]  = sinf(pr) * m;
    }
    __syncthreads();
    float e0 = emb[t], e1 = emb[t+128], e2 = emb[t+256];
    red[t] = e0 + e1 + e2; __syncthreads();
    for (int w = 64; w > 0; w >>= 1) { if (t < w) red[t] += red[t+w]; __syncthreads(); }
    float mean = red[0] * (1.0f/NC);
    __syncthreads();
    float d0 = e0-mean, d1 = e1-mean, d2 = e2-mean;
    red[t] = d0*d0 + d1*d1 + d2*d2; __syncthreads();
    for (int w = 64; w > 0; w >>= 1) { if (t < w) red[t] += red[t+w]; __syncthreads(); }
    float var = red[0] * (1.0f/NC);
    float inv = 1.0f / sqrtf(var + 1e-5f);
    q0[(size_t)row*NC + t]       = d0*inv*ln_g[t]      + ln_b[t];
    q0[(size_t)row*NC + t + 128] = d1*inv*ln_g[t+128]  + ln_b[t+128];
    q0[(size_t)row*NC + t + 256] = d2*inv*ln_g[t+256]  + ln_b[t+256];
}

// ---------------- kernel 3: generic [M,384]@[384,384] fp32 GEMM ----------------
__global__ __launch_bounds__(256) void k_gemm384(const float* __restrict__ A,
                                                 const float* __restrict__ W,
                                                 float* __restrict__ out) {
    __shared__ float As[16][68];
    __shared__ float Ws[16][68];
    int t = threadIdx.x;
    int tx = t & 15, ty = t >> 4;
    int rowbase = blockIdx.x * 64, colbase = blockIdx.y * 64;
    float acc[4][4] = {};
    for (int k0 = 0; k0 < NC; k0 += 16) {
        {
            int r = t >> 2, ja = (t & 3) << 2;
            float4 a4 = *(const float4*)(A + (size_t)(rowbase + r)*NC + k0 + ja);
            As[ja+0][r] = a4.x; As[ja+1][r] = a4.y; As[ja+2][r] = a4.z; As[ja+3][r] = a4.w;
        }
        {
            int kr = t >> 4, jw = (t & 15) << 2;
            float4 w4 = *(const float4*)(W + (size_t)(k0 + kr)*NC + colbase + jw);
            *(float4*)&Ws[kr][jw] = w4;
        }
        __syncthreads();
        #pragma unroll
        for (int kk = 0; kk < 16; ++kk) {
            float4 av = *(const float4*)&As[kk][ty<<2];
            float4 wv = *(const float4*)&Ws[kk][tx<<2];
            float aa[4] = {av.x, av.y, av.z, av.w};
            float ww[4] = {wv.x, wv.y, wv.z, wv.w};
            #pragma unroll
            for (int i = 0; i < 4; ++i)
                #pragma unroll
                for (int j = 0; j < 4; ++j)
                    acc[i][j] += aa[i]*ww[j];
        }
        __syncthreads();
    }
    #pragma unroll
    for (int i = 0; i < 4; ++i) {
        float4 o = make_float4(acc[i][0], acc[i][1], acc[i][2], acc[i][3]);
        *(float4*)(out + (size_t)(rowbase + (ty<<2) + i)*NC + colbase + (tx<<2)) = o;
    }
}

// ---------------- kernel 4: K x K overlap scores + top-16 per row ----------------
__global__ __launch_bounds__(256) void k_score_topk(const float* __restrict__ mu,
                                                    const float* __restrict__ Sg,
                                                    const float* __restrict__ maskp,
                                                    int* __restrict__ knn) {
    int b = blockIdx.x >> 9, i = blockIdx.x & 511;
    int t = threadIdx.x;
    __shared__ float swv[4];
    __shared__ int   swi[4];
    __shared__ int   winner;
    const float* mui = mu + (size_t)(b*NK + i)*3;
    const float* Sgi = Sg + (size_t)(b*NK + i)*9;
    float mi0 = mui[0], mi1 = mui[1], mi2 = mui[2];
    float S0 = Sgi[0], S1 = Sgi[1], S2 = Sgi[2], S4 = Sgi[4], S5 = Sgi[5], S8 = Sgi[8];
    float mski = maskp[b*NK + i];
    float cand[2];
    #pragma unroll
    for (int h = 0; h < 2; ++h) {
        int j = t + h*256;
        const float* muj = mu + (size_t)(b*NK + j)*3;
        const float* Sgj = Sg + (size_t)(b*NK + j)*9;
        float d0 = mi0-muj[0], d1 = mi1-muj[1], d2 = mi2-muj[2];
        float a00 = S0+Sgj[0]+1e-6f, a01 = S1+Sgj[1],       a02 = S2+Sgj[2];
        float a11 = S4+Sgj[4]+1e-6f, a12 = S5+Sgj[5],       a22 = S8+Sgj[8]+1e-6f;
        float c00 = a11*a22 - a12*a12;
        float c01 = a02*a12 - a01*a22;
        float c02 = a01*a12 - a02*a11;
        float c11 = a00*a22 - a02*a02;
        float c12 = a01*a02 - a00*a12;
        float c22 = a00*a11 - a01*a01;
        float det = a00*c00 + a01*c01 + a02*c02;
        float t0 = c00*d0 + c01*d1 + c02*d2;
        float t1 = c01*d0 + c11*d1 + c12*d2;
        float t2 = c02*d0 + c12*d1 + c22*d2;
        float maha = (d0*t0 + d1*t1 + d2*t2) / det;
        float score = -0.5f*(maha + logf(det));
        float mj = maskp[b*NK + j];
        cand[h] = (mski*mj < 0.5f) ? -1e9f : score;
    }
    int lane = t & 63, wv = t >> 6;
    for (int it = 0; it < NR; ++it) {
        float bv; int bi;
        if (cand[0] >= cand[1]) { bv = cand[0]; bi = t; }       // >= keeps smaller index on tie
        else                    { bv = cand[1]; bi = t + 256; }
        #pragma unroll
        for (int off = 32; off > 0; off >>= 1) {
            float v2 = __shfl_xor(bv, off);
            int   i2 = __shfl_xor(bi, off);
            if (v2 > bv || (v2 == bv && i2 < bi)) { bv = v2; bi = i2; }
        }
        if (lane == 0) { swv[wv] = bv; swi[wv] = bi; }
        __syncthreads();
        if (t == 0) {
            float B = swv[0]; int I = swi[0];
            #pragma unroll
            for (int w = 1; w < 4; ++w)
                if (swv[w] > B || (swv[w] == B && swi[w] < I)) { B = swv[w]; I = swi[w]; }
            knn[((size_t)(b*NK + i))*NR + it] = I;
            winner = I;
        }
        __syncthreads();
        int wn = winner;
        if (t == wn)        cand[0] = -INFINITY;
        if (t + 256 == wn)  cand[1] = -INFINITY;
    }
}

// ---------------- kernel 5: logits_full + argmax + store raw scaled logits ----------------
__global__ __launch_bounds__(256) void k_logits_argmax(const float* __restrict__ q,
                                                       const float* __restrict__ kmat,
                                                       const float* __restrict__ maskp,
                                                       int* __restrict__ j0,
                                                       float* __restrict__ lg_out) {
    int t = threadIdx.x;
    int rowbase = blockIdx.x << 4;
    int b = rowbase >> 12;
    __shared__ float kkT[16][NK];      // [c][p] transposed k chunk
    __shared__ float qqT[16][20];      // [c][row]
    __shared__ float sv[16][128];
    __shared__ int   si[16][128];
    int pg = t & 127, rg = t >> 7;     // 4 parents x 8 rows per thread
    float acc[8][4] = {};
    const float* kb = kmat + (size_t)b*NK*NC;
    for (int c0 = 0; c0 < NC; c0 += 16) {
        if (t < 64) {
            int r = t >> 2, ja = (t & 3) << 2;
            float4 a = *(const float4*)(q + (size_t)(rowbase + r)*NC + c0 + ja);
            qqT[ja+0][r] = a.x; qqT[ja+1][r] = a.y; qqT[ja+2][r] = a.z; qqT[ja+3][r] = a.w;
        }
        #pragma unroll
        for (int it2 = 0; it2 < 8; ++it2) {
            int id = it2*256 + t;
            int p = id >> 2, ja = (id & 3) << 2;
            float4 a = *(const float4*)(kb + (size_t)p*NC + c0 + ja);
            kkT[ja+0][p] = a.x; kkT[ja+1][p] = a.y; kkT[ja+2][p] = a.z; kkT[ja+3][p] = a.w;
        }
        __syncthreads();
        #pragma unroll
        for (int jj = 0; jj < 16; ++jj) {
            float4 kv = *(const float4*)&kkT[jj][pg<<2];
            float4 qa = *(const float4*)&qqT[jj][rg<<3];
            float4 qb = *(const float4*)&qqT[jj][(rg<<3)+4];
            float qv[8] = {qa.x,qa.y,qa.z,qa.w,qb.x,qb.y,qb.z,qb.w};
            float kk4[4] = {kv.x,kv.y,kv.z,kv.w};
            #pragma unroll
            for (int rr = 0; rr < 8; ++rr)
                #pragma unroll
                for (int cc = 0; cc < 4; ++cc)
                    acc[rr][cc] += qv[rr]*kk4[cc];
        }
        __syncthreads();
    }
    float mk[4];
    #pragma unroll
    for (int cc = 0; cc < 4; ++cc) mk[cc] = (maskp[b*NK + (pg<<2) + cc] - 1.0f)*1e9f;
    #pragma unroll
    for (int rr = 0; rr < 8; ++rr) {
        int rloc = (rg<<3) + rr;
        float raw[4];
        float bv = -INFINITY; int bj = 0;
        #pragma unroll
        for (int cc = 0; cc < 4; ++cc) {
            raw[cc] = acc[rr][cc]*INV_SQRT_C;
            float v = raw[cc] + mk[cc];
            if (v > bv) { bv = v; bj = cc; }
        }
        *(float4*)(lg_out + (size_t)(rowbase + rloc)*NK + (pg<<2)) =
            make_float4(raw[0], raw[1], raw[2], raw[3]);
        sv[rloc][pg] = bv;
        si[rloc][pg] = (pg<<2) + bj;
    }
    __syncthreads();
    if (t < 16) {
        float bv = -INFINITY; int bi = 0;
        for (int x = 0; x < 128; ++x) {        // ascending parent blocks: first-max kept
            float v = sv[t][x];
            if (v > bv) { bv = v; bi = si[t][x]; }
        }
        j0[rowbase + t] = bi;
    }
}

// ---------------- kernel 6: gathered attention epilogue — 16 rows/block ----------------
__global__ __launch_bounds__(256) void k_final(const float* __restrict__ logits,
                                               const float* __restrict__ vmat,
                                               const float* __restrict__ mu,
                                               const float* __restrict__ Sg,
                                               const float* __restrict__ node_mask,
                                               const int* __restrict__ j0,
                                               const int* __restrict__ knn,
                                               float* __restrict__ out_s0,
                                               float* __restrict__ out_mu0,
                                               float* __restrict__ out_Sig0,
                                               float* __restrict__ out_Bl,
                                               float* __restrict__ occ_part,
                                               float* __restrict__ loss_part) {
    int t = threadIdx.x;
    int rowbase = blockIdx.x << 4;
    int b = rowbase >> 12;
    int l  = t & 63;
    int sub = l >> 4, ll = l & 15;
    int r = ((t >> 6) << 2) + sub;          // 0..15, this thread's row
    int grow = rowbase + r;
    __shared__ float wl[16][17];
    __shared__ int   pidx[16][17];
    __shared__ float lred[16];
    __shared__ float msk[16];

    float m = node_mask[grow];
    int p = knn[((size_t)(b*NK + j0[grow]))*NR + ll];
    float v = logits[(size_t)grow*NK + p];
    // softmax over 16-lane group (node-mask shift is uniform per row -> softmax-invariant)
    float mx = v;
    #pragma unroll
    for (int off = 8; off > 0; off >>= 1) mx = fmaxf(mx, __shfl_xor(mx, off));
    float e = expf(v - mx);
    float sme = e;
    #pragma unroll
    for (int off = 8; off > 0; off >>= 1) sme += __shfl_xor(sme, off);
    float w = e / sme;
    wl[r][ll] = w;
    pidx[r][ll] = p;
    out_Bl[(size_t)rowbase*NR + t] = w;     // r*16+ll == t

    // mu0 / Sig0 / attach score within the 16-lane group
    const float* mur = mu + (size_t)(b*NK + p)*3;
    const float* Sgr = Sg + (size_t)(b*NK + p)*9;
    float mr0 = mur[0], mr1 = mur[1], mr2 = mur[2];
    float m0 = w*mr0, m1 = w*mr1, m2 = w*mr2;
    #pragma unroll
    for (int off = 8; off > 0; off >>= 1) {
        m0 += __shfl_xor(m0, off); m1 += __shfl_xor(m1, off); m2 += __shfl_xor(m2, off);
    }
    float d0 = mr0-m0, d1 = mr1-m1, d2 = mr2-m2;   // mu_sub - mu0 (sign cancels in maha)
    float a00 = Sgr[0], a01 = Sgr[1], a02 = Sgr[2];
    float a11 = Sgr[4], a12 = Sgr[5], a22 = Sgr[8];
    float p00 = w*(a00 + d0*d0), p01 = w*(a01 + d0*d1), p02 = w*(a02 + d0*d2);
    float p11 = w*(a11 + d1*d1), p12 = w*(a12 + d1*d2), p22 = w*(a22 + d2*d2);
    #pragma unroll
    for (int off = 8; off > 0; off >>= 1) {
        p00 += __shfl_xor(p00, off); p01 += __shfl_xor(p01, off); p02 += __shfl_xor(p02, off);
        p11 += __shfl_xor(p11, off); p12 += __shfl_xor(p12, off); p22 += __shfl_xor(p22, off);
    }
    float c00 = a11*a22 - a12*a12;
    float c01 = a02*a12 - a01*a22;
    float c02 = a01*a12 - a02*a11;
    float c11 = a00*a22 - a02*a02;
    float c12 = a01*a02 - a00*a12;
    float c22 = a00*a11 - a01*a01;
    float det = a00*c00 + a01*c01 + a02*c02;
    float t0 = c00*d0 + c01*d1 + c02*d2;
    float t1 = c01*d0 + c11*d1 + c12*d2;
    float t2 = c02*d0 + c12*d1 + c22*d2;
    float maha = (d0*t0 + d1*t1 + d2*t2) / det;
    float score = -0.5f*(maha + logf(det));
    float lp = w*score;
    #pragma unroll
    for (int off = 8; off > 0; off >>= 1) lp += __shfl_xor(lp, off);
    if (ll == 0) {
        out_mu0[(size_t)grow*3+0] = m0;
        out_mu0[(size_t)grow*3+1] = m1;
        out_mu0[(size_t)grow*3+2] = m2;
        float* o = out_Sig0 + (size_t)grow*9;
        o[0]=p00+F_JITTER; o[1]=p01;          o[2]=p02;
        o[3]=p01;          o[4]=p11+F_JITTER; o[5]=p12;
        o[6]=p02;          o[7]=p12;          o[8]=p22+F_JITTER;
        lred[r] = m*lp;
        msk[r] = m;
    }
    // sliced occ accumulation: contention / NSLICE
    atomicAdd(&occ_part[(size_t)(blockIdx.x & (NSLICE-1))*(NB*NK) + b*NK + p], w*m);
    __syncthreads();
    if (t == 0) {
        float s = 0.f;
        #pragma unroll
        for (int i = 0; i < 16; ++i) s += lred[i];
        loss_part[blockIdx.x] = s;          // plain store, no atomic
    }
    // PV: 16 rows x 96 float4 cols = 1536 tasks over 256 threads (6 iters), coalesced
    const float4* vb = (const float4*)(vmat + (size_t)b*NK*NC);
    #pragma unroll
    for (int it = 0; it < 6; ++it) {
        int id = it*256 + t;
        int row = id / 96;
        int col = id - row*96;
        float4 a = make_float4(0.f, 0.f, 0.f, 0.f);
        #pragma unroll
        for (int r2 = 0; r2 < NR; ++r2) {
            float ww = wl[row][r2];
            float4 vv = vb[(size_t)pidx[row][r2]*96 + col];
            a.x += ww*vv.x; a.y += ww*vv.y; a.z += ww*vv.z; a.w += ww*vv.w;
        }
        float mm = msk[row];
        a.x *= mm; a.y *= mm; a.z *= mm; a.w *= mm;
        ((float4*)(out_s0 + (size_t)(rowbase + row)*NC))[col] = a;
    }
}

// ---------------- kernel 7: occ-slice reduce + normalize + loss ----------------
__global__ __launch_bounds__(1024) void k_finalize(const float* __restrict__ occ_part,
                                                   const float* __restrict__ Lsum,
                                                   const float* __restrict__ loss_part,
                                                   float* __restrict__ out_occn,
                                                   float* __restrict__ out_loss) {
    int t = threadIdx.x;               // 0..1023 <-> (b,p)
    __shared__ float red[1024];
    float s = 0.f;
    for (int sl = 0; sl < NSLICE; ++sl) s += occ_part[(size_t)sl*(NB*NK) + t];
    red[t] = s; __syncthreads();
    // per-batch halves reduce independently
    for (int w = 256; w > 0; w >>= 1) {
        if ((t & 511) < w) red[t] += red[t+w];
        __syncthreads();
    }
    float tot = red[t & 512];          // red[0] for b=0, red[512] for b=1
    float occn = s / fmaxf(tot, 1e-9f);
    __syncthreads();
    out_occn[t] = occn;
    // loss: sum 512 per-block partials
    float lp = (t < 512) ? loss_part[t] : 0.f;
    red[t] = lp; __syncthreads();
    for (int w = 512; w > 0; w >>= 1) {
        if (t < w) red[t] += red[t+w];
        __syncthreads();
    }
    if (t == 0) {
        float dnm = fmaxf(Lsum[0] + Lsum[1], 1.0f);
        out_loss[0] = -(red[0] / dnm);   // W_ATTACH=1, W_ENTB=0
    }
}

extern "C" void kernel_launch(void* const* d_in, const int* in_sizes, int n_in,
                              void* d_out, int out_size, void* d_ws, size_t ws_size,
                              hipStream_t stream) {
    const float* s_parent   = (const float*)d_in[0];
    const float* mu_parent  = (const float*)d_in[1];
    const float* Sig_parent = (const float*)d_in[2];
    const float* mask_par   = (const float*)d_in[3];
    const float* node_mask  = (const float*)d_in[4];
    const int*   res_idx    = (const int*)d_in[5];
    const float* Bm         = (const float*)d_in[6];
    const float* Wq         = (const float*)d_in[7];
    const float* Wk         = (const float*)d_in[8];
    const float* Wv         = (const float*)d_in[9];
    const float* ln_g       = (const float*)d_in[10];
    const float* ln_b       = (const float*)d_in[11];

    float* ws = (float*)d_ws;
    // region A shared: q0 (k_q0 -> gemm) then logits (k_logits_argmax -> k_final)
    const size_t OFF_A   = 0;                               // max(3145728, 4194304)
    const size_t OFF_Q   = OFF_A   + (size_t)NB*NN*NK;      // 4194304
    const size_t OFF_K   = OFF_Q   + (size_t)NB*NN*NC;      // +3145728
    const size_t OFF_V   = OFF_K   + (size_t)NB*NK*NC;      // +393216
    const size_t OFF_J0  = OFF_V   + (size_t)NB*NK*NC;      // +393216 (ints)
    const size_t OFF_KNN = OFF_J0  + (size_t)NB*NN;         // +8192 (ints)
    const size_t OFF_LS  = OFF_KNN + (size_t)NB*NK*NR;      // +16384
    const size_t OFF_LP  = OFF_LS  + 16;                    // 512 loss partials
    float* q0     = ws + OFF_A;
    float* logits = ws + OFF_A;
    float* q      = ws + OFF_Q;
    float* kmat   = ws + OFF_K;
    float* vmat   = ws + OFF_V;
    int*   j0     = (int*)(ws + OFF_J0);
    int*   knn    = (int*)(ws + OFF_KNN);
    float* Lsum   = ws + OFF_LS;
    float* lpart  = ws + OFF_LP;
    // occ_part [64][1024] aliases the q region — q is dead after k_logits_argmax
    float* occ_part = ws + OFF_Q;

    float* out      = (float*)d_out;
    float* out_s0   = out;
    float* out_mu0  = out      + (size_t)NB*NN*NC;
    float* out_Sig0 = out_mu0  + (size_t)NB*NN*3;
    float* out_Bl   = out_Sig0 + (size_t)NB*NN*9;
    float* out_occn = out_Bl   + (size_t)NB*NN*NR;
    float* out_loss = out_occn + (size_t)NB*NK;

    (void)in_sizes; (void)n_in; (void)out_size; (void)ws_size;

    k_masksum<<<NB, 256, 0, stream>>>(node_mask, Lsum);
    k_q0<<<NB*NN, 128, 0, stream>>>(res_idx, node_mask, Bm, ln_g, ln_b, Lsum, q0);
    k_gemm384<<<dim3((NB*NN)/64, NC/64), 256, 0, stream>>>(q0, Wq, q);
    k_gemm384<<<dim3((NB*NK)/64, NC/64), 256, 0, stream>>>(s_parent, Wk, kmat);
    k_gemm384<<<dim3((NB*NK)/64, NC/64), 256, 0, stream>>>(s_parent, Wv, vmat);
    k_score_topk<<<NB*NK, 256, 0, stream>>>(mu_parent, Sig_parent, mask_par, knn);
    k_logits_argmax<<<(NB*NN)/16, 256, 0, stream>>>(q, kmat, mask_par, j0, logits);
    // q is dead from here; zero the occ slices that alias it
    hipMemsetAsync(occ_part, 0, (size_t)NSLICE*NB*NK*sizeof(float), stream);
    k_final<<<(NB*NN)/16, 256, 0, stream>>>(logits, vmat, mu_parent, Sig_parent, node_mask,
                                            j0, knn, out_s0, out_mu0, out_Sig0, out_Bl,
                                            occ_part, lpart);
    k_finalize<<<1, 1024, 0, stream>>>(occ_part, Lsum, lpart, out_occn, out_loss);
}

// Round 4
// 167.415 us; speedup vs baseline: 2.0412x; 1.2912x over previous
//
#include <hip/hip_runtime.h>
#include <math.h>

#define NB 2
#define NN 4096
#define NK 512
#define NC 384
#define NR 16
#define NCH 192
#define NSLICE 64

static constexpr float INV_SQRT_C = 0.051031036307982884f; // 1/sqrt(384)
static constexpr float TWO_PI     = 6.283185307179586f;
static constexpr float F_JITTER   = 1e-4f;

typedef __attribute__((ext_vector_type(8))) short short8;
typedef __attribute__((ext_vector_type(4))) float f32x4;
typedef __attribute__((ext_vector_type(4))) unsigned short us4;

__device__ __forceinline__ void split3(float x, unsigned short& h, unsigned short& m_, unsigned short& l_) {
    unsigned int xi = __float_as_uint(x);
    unsigned int uh = (xi + 0x7fffu + ((xi >> 16) & 1u)) >> 16;
    float fh = __uint_as_float(uh << 16);
    float r  = x - fh;                      // exact (<=16 significant bits)
    unsigned int ri = __float_as_uint(r);
    unsigned int um = (ri + 0x7fffu + ((ri >> 16) & 1u)) >> 16;
    float fm = __uint_as_float(um << 16);
    float r2 = r - fm;                      // exact (<=8 significant bits)
    unsigned int r2i = __float_as_uint(r2);
    unsigned int ul = (r2i + 0x7fffu + ((r2i >> 16) & 1u)) >> 16;
    h = (unsigned short)uh; m_ = (unsigned short)um; l_ = (unsigned short)ul;
}

// ---------------- kernel 1: per-batch node_mask sum ----------------
__global__ __launch_bounds__(256) void k_masksum(const float* __restrict__ node_mask,
                                                 float* __restrict__ Lsum) {
    int b = blockIdx.x, t = threadIdx.x;
    __shared__ float red[256];
    float s = 0.f;
    for (int n = t; n < NN; n += 256) s += node_mask[b*NN + n];
    red[t] = s; __syncthreads();
    for (int w = 128; w > 0; w >>= 1) { if (t < w) red[t] += red[t+w]; __syncthreads(); }
    if (t == 0) Lsum[b] = red[0];
}

// ---------------- kernel 2: fourier emb + layernorm -> q0 ----------------
__global__ __launch_bounds__(128) void k_q0(const int* __restrict__ res_idx,
                                            const float* __restrict__ node_mask,
                                            const float* __restrict__ Bm,
                                            const float* __restrict__ ln_g,
                                            const float* __restrict__ ln_b,
                                            const float* __restrict__ Lsum,
                                            float* __restrict__ q0) {
    int row = blockIdx.x, t = threadIdx.x;
    int b = row >> 12;
    __shared__ float emb[NC];
    __shared__ float red[128];
    float m = node_mask[row];
    float Lb = fmaxf(Lsum[b], 1.0f);
    float denom = fmaxf(Lb - 1.0f, 1.0f);
    int ri = res_idx[row];
    ri = ri < 0 ? 0 : (ri > 4095 ? 4095 : ri);
    float pos = fminf(fmaxf((float)ri / denom, 0.f), 1.f);
    for (int i = t; i < NCH; i += 128) {
        float pr = TWO_PI * pos * Bm[i];
        emb[i]      = cosf(pr) * m;
        emb[i+NCH]  = sinf(pr) * m;
    }
    __syncthreads();
    float e0 = emb[t], e1 = emb[t+128], e2 = emb[t+256];
    red[t] = e0 + e1 + e2; __syncthreads();
    for (int w = 64; w > 0; w >>= 1) { if (t < w) red[t] += red[t+w]; __syncthreads(); }
    float mean = red[0] * (1.0f/NC);
    __syncthreads();
    float d0 = e0-mean, d1 = e1-mean, d2 = e2-mean;
    red[t] = d0*d0 + d1*d1 + d2*d2; __syncthreads();
    for (int w = 64; w > 0; w >>= 1) { if (t < w) red[t] += red[t+w]; __syncthreads(); }
    float var = red[0] * (1.0f/NC);
    float inv = 1.0f / sqrtf(var + 1e-5f);
    q0[(size_t)row*NC + t]       = d0*inv*ln_g[t]      + ln_b[t];
    q0[(size_t)row*NC + t + 128] = d1*inv*ln_g[t+128]  + ln_b[t+128];
    q0[(size_t)row*NC + t + 256] = d2*inv*ln_g[t+256]  + ln_b[t+256];
}

// ---------------- kernel 3: [M,384]@[384,384] fp32 GEMM (B row-major) ----------------
__global__ __launch_bounds__(256) void k_gemm384(const float* __restrict__ A,
                                                 const float* __restrict__ W,
                                                 float* __restrict__ out) {
    __shared__ float As[16][68];
    __shared__ float Ws[16][68];
    int t = threadIdx.x;
    int tx = t & 15, ty = t >> 4;
    int rowbase = blockIdx.x * 64, colbase = blockIdx.y * 64;
    float acc[4][4] = {};
    for (int k0 = 0; k0 < NC; k0 += 16) {
        {
            int r = t >> 2, ja = (t & 3) << 2;
            float4 a4 = *(const float4*)(A + (size_t)(rowbase + r)*NC + k0 + ja);
            As[ja+0][r] = a4.x; As[ja+1][r] = a4.y; As[ja+2][r] = a4.z; As[ja+3][r] = a4.w;
        }
        {
            int kr = t >> 4, jw = (t & 15) << 2;
            float4 w4 = *(const float4*)(W + (size_t)(k0 + kr)*NC + colbase + jw);
            *(float4*)&Ws[kr][jw] = w4;
        }
        __syncthreads();
        #pragma unroll
        for (int kk = 0; kk < 16; ++kk) {
            float4 av = *(const float4*)&As[kk][ty<<2];
            float4 wv = *(const float4*)&Ws[kk][tx<<2];
            float aa[4] = {av.x, av.y, av.z, av.w};
            float ww[4] = {wv.x, wv.y, wv.z, wv.w};
            #pragma unroll
            for (int i = 0; i < 4; ++i)
                #pragma unroll
                for (int j = 0; j < 4; ++j)
                    acc[i][j] += aa[i]*ww[j];
        }
        __syncthreads();
    }
    #pragma unroll
    for (int i = 0; i < 4; ++i) {
        float4 o = make_float4(acc[i][0], acc[i][1], acc[i][2], acc[i][3]);
        *(float4*)(out + (size_t)(rowbase + (ty<<2) + i)*NC + colbase + (tx<<2)) = o;
    }
}

// -------- kernel 3b: out[m][n] = sum_k A[m][k]*B[n][k]  (B^T GEMM, for G^t = k @ Wq^T) --------
__global__ __launch_bounds__(256) void k_gemm384_bt(const float* __restrict__ A,
                                                    const float* __restrict__ Bt,
                                                    float* __restrict__ out) {
    __shared__ float As[16][68];
    __shared__ float Ws[16][68];
    int t = threadIdx.x;
    int tx = t & 15, ty = t >> 4;
    int rowbase = blockIdx.x * 64, colbase = blockIdx.y * 64;
    float acc[4][4] = {};
    for (int k0 = 0; k0 < NC; k0 += 16) {
        {
            int r = t >> 2, ja = (t & 3) << 2;
            float4 a4 = *(const float4*)(A + (size_t)(rowbase + r)*NC + k0 + ja);
            As[ja+0][r] = a4.x; As[ja+1][r] = a4.y; As[ja+2][r] = a4.z; As[ja+3][r] = a4.w;
        }
        {
            int r = t >> 2, jb = (t & 3) << 2;
            float4 b4 = *(const float4*)(Bt + (size_t)(colbase + r)*NC + k0 + jb);
            Ws[jb+0][r] = b4.x; Ws[jb+1][r] = b4.y; Ws[jb+2][r] = b4.z; Ws[jb+3][r] = b4.w;
        }
        __syncthreads();
        #pragma unroll
        for (int kk = 0; kk < 16; ++kk) {
            float4 av = *(const float4*)&As[kk][ty<<2];
            float4 wv = *(const float4*)&Ws[kk][tx<<2];
            float aa[4] = {av.x, av.y, av.z, av.w};
            float ww[4] = {wv.x, wv.y, wv.z, wv.w};
            #pragma unroll
            for (int i = 0; i < 4; ++i)
                #pragma unroll
                for (int j = 0; j < 4; ++j)
                    acc[i][j] += aa[i]*ww[j];
        }
        __syncthreads();
    }
    #pragma unroll
    for (int i = 0; i < 4; ++i) {
        float4 o = make_float4(acc[i][0], acc[i][1], acc[i][2], acc[i][3]);
        *(float4*)(out + (size_t)(rowbase + (ty<<2) + i)*NC + colbase + (tx<<2)) = o;
    }
}

// ---------------- kernel 4: K x K overlap scores + top-16 per row ----------------
__global__ __launch_bounds__(256) void k_score_topk(const float* __restrict__ mu,
                                                    const float* __restrict__ Sg,
                                                    const float* __restrict__ maskp,
                                                    int* __restrict__ knn) {
    int b = blockIdx.x >> 9, i = blockIdx.x & 511;
    int t = threadIdx.x;
    __shared__ float swv[4];
    __shared__ int   swi[4];
    __shared__ int   winner;
    const float* mui = mu + (size_t)(b*NK + i)*3;
    const float* Sgi = Sg + (size_t)(b*NK + i)*9;
    float mi0 = mui[0], mi1 = mui[1], mi2 = mui[2];
    float S0 = Sgi[0], S1 = Sgi[1], S2 = Sgi[2], S4 = Sgi[4], S5 = Sgi[5], S8 = Sgi[8];
    float mski = maskp[b*NK + i];
    float cand[2];
    #pragma unroll
    for (int h = 0; h < 2; ++h) {
        int j = t + h*256;
        const float* muj = mu + (size_t)(b*NK + j)*3;
        const float* Sgj = Sg + (size_t)(b*NK + j)*9;
        float d0 = mi0-muj[0], d1 = mi1-muj[1], d2 = mi2-muj[2];
        float a00 = S0+Sgj[0]+1e-6f, a01 = S1+Sgj[1],       a02 = S2+Sgj[2];
        float a11 = S4+Sgj[4]+1e-6f, a12 = S5+Sgj[5],       a22 = S8+Sgj[8]+1e-6f;
        float c00 = a11*a22 - a12*a12;
        float c01 = a02*a12 - a01*a22;
        float c02 = a01*a12 - a02*a11;
        float c11 = a00*a22 - a02*a02;
        float c12 = a01*a02 - a00*a12;
        float c22 = a00*a11 - a01*a01;
        float det = a00*c00 + a01*c01 + a02*c02;
        float t0 = c00*d0 + c01*d1 + c02*d2;
        float t1 = c01*d0 + c11*d1 + c12*d2;
        float t2 = c02*d0 + c12*d1 + c22*d2;
        float maha = (d0*t0 + d1*t1 + d2*t2) / det;
        float score = -0.5f*(maha + logf(det));
        float mj = maskp[b*NK + j];
        cand[h] = (mski*mj < 0.5f) ? -1e9f : score;
    }
    int lane = t & 63, wv = t >> 6;
    for (int it = 0; it < NR; ++it) {
        float bv; int bi;
        if (cand[0] >= cand[1]) { bv = cand[0]; bi = t; }
        else                    { bv = cand[1]; bi = t + 256; }
        #pragma unroll
        for (int off = 32; off > 0; off >>= 1) {
            float v2 = __shfl_xor(bv, off);
            int   i2 = __shfl_xor(bi, off);
            if (v2 > bv || (v2 == bv && i2 < bi)) { bv = v2; bi = i2; }
        }
        if (lane == 0) { swv[wv] = bv; swi[wv] = bi; }
        __syncthreads();
        if (t == 0) {
            float B = swv[0]; int I = swi[0];
            #pragma unroll
            for (int w = 1; w < 4; ++w)
                if (swv[w] > B || (swv[w] == B && swi[w] < I)) { B = swv[w]; I = swi[w]; }
            knn[((size_t)(b*NK + i))*NR + it] = I;
            winner = I;
        }
        __syncthreads();
        int wn = winner;
        if (t == wn)        cand[0] = -INFINITY;
        if (t + 256 == wn)  cand[1] = -INFINITY;
    }
}

// -------- kernel 5: logits = q0 @ Gt^T via MFMA 3-split bf16 (6 passes) + argmax partials --------
// tile: 128 rows x 64 cols, 4 waves (2x2), per-wave 64x32 (4x2 frags of 16x16)
__global__ __launch_bounds__(256) void k_logits_mfma(const float* __restrict__ q0,
                                                     const float* __restrict__ Gt,
                                                     const float* __restrict__ maskp,
                                                     float* __restrict__ logits,
                                                     float* __restrict__ pmaxv,
                                                     int*   __restrict__ pmaxi) {
    int bid = blockIdx.x;
    int wg = (bid & 7) * 64 + (bid >> 3);      // XCD-chunked swizzle (512 = 8*64)
    int b  = wg >> 8;
    int r8 = (wg >> 3) & 31;
    int cb = wg & 7;
    int rowbase = r8 << 7;
    int colbase = cb << 6;

    __shared__ __align__(16) unsigned short Ah[128][40];
    __shared__ __align__(16) unsigned short Am[128][40];
    __shared__ __align__(16) unsigned short Al[128][40];
    __shared__ __align__(16) unsigned short Bh[64][40];
    __shared__ __align__(16) unsigned short Bm2[64][40];
    __shared__ __align__(16) unsigned short Bl[64][40];
    __shared__ float rmv[128][2];
    __shared__ int   rmi[128][2];

    int t = threadIdx.x;
    int lane = t & 63, wv = t >> 6;
    int wr = wv >> 1, wc = wv & 1;
    int a = lane & 15, g = lane >> 4;

    const float* Ag = q0 + ((size_t)(b << 12) + rowbase) * NC;
    const float* Bg = Gt + ((size_t)(b << 9) + colbase) * NC;

    f32x4 acc[4][2];
    #pragma unroll
    for (int i = 0; i < 4; ++i)
        #pragma unroll
        for (int j = 0; j < 2; ++j)
            acc[i][j] = (f32x4){0.f, 0.f, 0.f, 0.f};

    for (int k0 = 0; k0 < NC; k0 += 32) {
        __syncthreads();
        #pragma unroll
        for (int i = 0; i < 4; ++i) {           // A: 128 rows x 32 f32 = 1024 float4
            int id = i*256 + t;
            int row = id >> 3, seg = id & 7;
            float4 v = *(const float4*)(Ag + (size_t)row*NC + k0 + (seg << 2));
            unsigned short h0,m0,l0,h1,m1,l1,h2,m2,l2,h3,m3,l3;
            split3(v.x, h0, m0, l0); split3(v.y, h1, m1, l1);
            split3(v.z, h2, m2, l2); split3(v.w, h3, m3, l3);
            *(us4*)&Ah[row][seg << 2] = (us4){h0, h1, h2, h3};
            *(us4*)&Am[row][seg << 2] = (us4){m0, m1, m2, m3};
            *(us4*)&Al[row][seg << 2] = (us4){l0, l1, l2, l3};
        }
        #pragma unroll
        for (int i = 0; i < 2; ++i) {           // B: 64 rows x 32 f32 = 512 float4
            int id = i*256 + t;
            int row = id >> 3, seg = id & 7;
            float4 v = *(const float4*)(Bg + (size_t)row*NC + k0 + (seg << 2));
            unsigned short h0,m0,l0,h1,m1,l1,h2,m2,l2,h3,m3,l3;
            split3(v.x, h0, m0, l0); split3(v.y, h1, m1, l1);
            split3(v.z, h2, m2, l2); split3(v.w, h3, m3, l3);
            *(us4*)&Bh[row][seg << 2]  = (us4){h0, h1, h2, h3};
            *(us4*)&Bm2[row][seg << 2] = (us4){m0, m1, m2, m3};
            *(us4*)&Bl[row][seg << 2]  = (us4){l0, l1, l2, l3};
        }
        __syncthreads();
        short8 afh[4], afm[4], afl[4];
        #pragma unroll
        for (int fr = 0; fr < 4; ++fr) {
            int r = (wr << 6) + (fr << 4) + a;
            afh[fr] = *(const short8*)&Ah[r][g << 3];
            afm[fr] = *(const short8*)&Am[r][g << 3];
            afl[fr] = *(const short8*)&Al[r][g << 3];
        }
        #pragma unroll
        for (int fc = 0; fc < 2; ++fc) {
            int c = (wc << 5) + (fc << 4) + a;
            short8 bh = *(const short8*)&Bh[c][g << 3];
            short8 bm = *(const short8*)&Bm2[c][g << 3];
            short8 bl = *(const short8*)&Bl[c][g << 3];
            #pragma unroll
            for (int fr = 0; fr < 4; ++fr) {
                acc[fr][fc] = __builtin_amdgcn_mfma_f32_16x16x32_bf16(afh[fr], bh, acc[fr][fc], 0, 0, 0);
                acc[fr][fc] = __builtin_amdgcn_mfma_f32_16x16x32_bf16(afh[fr], bm, acc[fr][fc], 0, 0, 0);
                acc[fr][fc] = __builtin_amdgcn_mfma_f32_16x16x32_bf16(afm[fr], bh, acc[fr][fc], 0, 0, 0);
                acc[fr][fc] = __builtin_amdgcn_mfma_f32_16x16x32_bf16(afh[fr], bl, acc[fr][fc], 0, 0, 0);
                acc[fr][fc] = __builtin_amdgcn_mfma_f32_16x16x32_bf16(afl[fr], bh, acc[fr][fc], 0, 0, 0);
                acc[fr][fc] = __builtin_amdgcn_mfma_f32_16x16x32_bf16(afm[fr], bm, acc[fr][fc], 0, 0, 0);
            }
        }
    }
    // epilogue: scale, store logits, masked per-row argmax partial
    float mk[2];
    #pragma unroll
    for (int fc = 0; fc < 2; ++fc)
        mk[fc] = (maskp[(b << 9) + colbase + (wc << 5) + (fc << 4) + a] - 1.0f) * 1e9f;
    int colg0 = colbase + (wc << 5) + a;
    #pragma unroll
    for (int fr = 0; fr < 4; ++fr) {
        #pragma unroll
        for (int reg = 0; reg < 4; ++reg) {
            int rloc = (wr << 6) + (fr << 4) + (g << 2) + reg;
            size_t rowg = (size_t)(b << 12) + rowbase + rloc;
            float v0 = acc[fr][0][reg] * INV_SQRT_C;
            float v1 = acc[fr][1][reg] * INV_SQRT_C;
            logits[rowg * NK + colg0]      = v0;
            logits[rowg * NK + colg0 + 16] = v1;
            float bv = v0 + mk[0]; int bc = colg0;
            float w1 = v1 + mk[1];
            if (w1 > bv) { bv = w1; bc = colg0 + 16; }
            #pragma unroll
            for (int off = 1; off < 16; off <<= 1) {
                float v2 = __shfl_xor(bv, off);
                int   c2 = __shfl_xor(bc, off);
                if (v2 > bv || (v2 == bv && c2 < bc)) { bv = v2; bc = c2; }
            }
            if (a == 0) { rmv[rloc][wc] = bv; rmi[rloc][wc] = bc; }
        }
    }
    __syncthreads();
    if (t < 128) {
        float v0 = rmv[t][0], v1 = rmv[t][1];
        int   c0 = rmi[t][0], c1 = rmi[t][1];
        float bv = v0; int bc = c0;
        if (v1 > bv) { bv = v1; bc = c1; }     // wc=1 cols are larger: strict >
        pmaxv[(((size_t)(b << 3) + cb) << 12) + rowbase + t] = bv;
        pmaxi[(((size_t)(b << 3) + cb) << 12) + rowbase + t] = bc;
    }
}

// ---------------- kernel 6: gathered attention epilogue — 16 rows/block ----------------
__global__ __launch_bounds__(256) void k_final(const float* __restrict__ logits,
                                               const float* __restrict__ vmat,
                                               const float* __restrict__ mu,
                                               const float* __restrict__ Sg,
                                               const float* __restrict__ node_mask,
                                               const float* __restrict__ pmaxv,
                                               const int*   __restrict__ pmaxi,
                                               const int* __restrict__ knn,
                                               float* __restrict__ out_s0,
                                               float* __restrict__ out_mu0,
                                               float* __restrict__ out_Sig0,
                                               float* __restrict__ out_Bl,
                                               float* __restrict__ occ_part,
                                               float* __restrict__ loss_part) {
    int t = threadIdx.x;
    int rowbase = blockIdx.x << 4;
    int b = rowbase >> 12;
    int l  = t & 63;
    int sub = l >> 4, ll = l & 15;
    int r = ((t >> 6) << 2) + sub;          // 0..15, this thread's row
    int grow = rowbase + r;
    __shared__ float wl[16][17];
    __shared__ int   pidx[16][17];
    __shared__ float lred[16];
    __shared__ float msk[16];
    __shared__ int   j0s[16];

    if (t < 16) {                            // combine 8 argmax partials -> j0
        int rowb = (rowbase & 4095) + t;
        float bv = -INFINITY; int bj = 0;
        #pragma unroll
        for (int cbk = 0; cbk < 8; ++cbk) {
            size_t idx = (((size_t)(b << 3) + cbk) << 12) + rowb;
            float v = pmaxv[idx];
            if (v > bv) { bv = v; bj = pmaxi[idx]; }
        }
        j0s[t] = bj;
    }
    __syncthreads();

    float m = node_mask[grow];
    int p = knn[((size_t)(b*NK + j0s[r]))*NR + ll];
    float v = logits[(size_t)grow*NK + p];
    float mx = v;
    #pragma unroll
    for (int off = 8; off > 0; off >>= 1) mx = fmaxf(mx, __shfl_xor(mx, off));
    float e = expf(v - mx);
    float sme = e;
    #pragma unroll
    for (int off = 8; off > 0; off >>= 1) sme += __shfl_xor(sme, off);
    float w = e / sme;
    wl[r][ll] = w;
    pidx[r][ll] = p;
    out_Bl[(size_t)rowbase*NR + t] = w;     // r*16+ll == t

    const float* mur = mu + (size_t)(b*NK + p)*3;
    const float* Sgr = Sg + (size_t)(b*NK + p)*9;
    float mr0 = mur[0], mr1 = mur[1], mr2 = mur[2];
    float m0 = w*mr0, m1 = w*mr1, m2 = w*mr2;
    #pragma unroll
    for (int off = 8; off > 0; off >>= 1) {
        m0 += __shfl_xor(m0, off); m1 += __shfl_xor(m1, off); m2 += __shfl_xor(m2, off);
    }
    float d0 = mr0-m0, d1 = mr1-m1, d2 = mr2-m2;
    float a00 = Sgr[0], a01 = Sgr[1], a02 = Sgr[2];
    float a11 = Sgr[4], a12 = Sgr[5], a22 = Sgr[8];
    float p00 = w*(a00 + d0*d0), p01 = w*(a01 + d0*d1), p02 = w*(a02 + d0*d2);
    float p11 = w*(a11 + d1*d1), p12 = w*(a12 + d1*d2), p22 = w*(a22 + d2*d2);
    #pragma unroll
    for (int off = 8; off > 0; off >>= 1) {
        p00 += __shfl_xor(p00, off); p01 += __shfl_xor(p01, off); p02 += __shfl_xor(p02, off);
        p11 += __shfl_xor(p11, off); p12 += __shfl_xor(p12, off); p22 += __shfl_xor(p22, off);
    }
    float c00 = a11*a22 - a12*a12;
    float c01 = a02*a12 - a01*a22;
    float c02 = a01*a12 - a02*a11;
    float c11 = a00*a22 - a02*a02;
    float c12 = a01*a02 - a00*a12;
    float c22 = a00*a11 - a01*a01;
    float det = a00*c00 + a01*c01 + a02*c02;
    float t0 = c00*d0 + c01*d1 + c02*d2;
    float t1 = c01*d0 + c11*d1 + c12*d2;
    float t2 = c02*d0 + c12*d1 + c22*d2;
    float maha = (d0*t0 + d1*t1 + d2*t2) / det;
    float score = -0.5f*(maha + logf(det));
    float lp = w*score;
    #pragma unroll
    for (int off = 8; off > 0; off >>= 1) lp += __shfl_xor(lp, off);
    if (ll == 0) {
        out_mu0[(size_t)grow*3+0] = m0;
        out_mu0[(size_t)grow*3+1] = m1;
        out_mu0[(size_t)grow*3+2] = m2;
        float* o = out_Sig0 + (size_t)grow*9;
        o[0]=p00+F_JITTER; o[1]=p01;          o[2]=p02;
        o[3]=p01;          o[4]=p11+F_JITTER; o[5]=p12;
        o[6]=p02;          o[7]=p12;          o[8]=p22+F_JITTER;
        lred[r] = m*lp;
        msk[r] = m;
    }
    atomicAdd(&occ_part[(size_t)(blockIdx.x & (NSLICE-1))*(NB*NK) + b*NK + p], w*m);
    __syncthreads();
    if (t == 0) {
        float s = 0.f;
        #pragma unroll
        for (int i = 0; i < 16; ++i) s += lred[i];
        loss_part[blockIdx.x] = s;
    }
    const float4* vb = (const float4*)(vmat + (size_t)b*NK*NC);
    #pragma unroll
    for (int it = 0; it < 6; ++it) {
        int id = it*256 + t;
        int row = id / 96;
        int col = id - row*96;
        float4 acc4 = make_float4(0.f, 0.f, 0.f, 0.f);
        #pragma unroll
        for (int r2 = 0; r2 < NR; ++r2) {
            float ww = wl[row][r2];
            float4 vv = vb[(size_t)pidx[row][r2]*96 + col];
            acc4.x += ww*vv.x; acc4.y += ww*vv.y; acc4.z += ww*vv.z; acc4.w += ww*vv.w;
        }
        float mm = msk[row];
        acc4.x *= mm; acc4.y *= mm; acc4.z *= mm; acc4.w *= mm;
        ((float4*)(out_s0 + (size_t)(rowbase + row)*NC))[col] = acc4;
    }
}

// ---------------- kernel 7: occ-slice reduce + normalize + loss ----------------
__global__ __launch_bounds__(1024) void k_finalize(const float* __restrict__ occ_part,
                                                   const float* __restrict__ Lsum,
                                                   const float* __restrict__ loss_part,
                                                   float* __restrict__ out_occn,
                                                   float* __restrict__ out_loss) {
    int t = threadIdx.x;
    __shared__ float red[1024];
    float s = 0.f;
    for (int sl = 0; sl < NSLICE; ++sl) s += occ_part[(size_t)sl*(NB*NK) + t];
    red[t] = s; __syncthreads();
    for (int w = 256; w > 0; w >>= 1) {
        if ((t & 511) < w) red[t] += red[t+w];
        __syncthreads();
    }
    float tot = red[t & 512];
    float occn = s / fmaxf(tot, 1e-9f);
    __syncthreads();
    out_occn[t] = occn;
    float lp = (t < 512) ? loss_part[t] : 0.f;
    red[t] = lp; __syncthreads();
    for (int w = 512; w > 0; w >>= 1) {
        if (t < w) red[t] += red[t+w];
        __syncthreads();
    }
    if (t == 0) {
        float dnm = fmaxf(Lsum[0] + Lsum[1], 1.0f);
        out_loss[0] = -(red[0] / dnm);
    }
}

extern "C" void kernel_launch(void* const* d_in, const int* in_sizes, int n_in,
                              void* d_out, int out_size, void* d_ws, size_t ws_size,
                              hipStream_t stream) {
    const float* s_parent   = (const float*)d_in[0];
    const float* mu_parent  = (const float*)d_in[1];
    const float* Sig_parent = (const float*)d_in[2];
    const float* mask_par   = (const float*)d_in[3];
    const float* node_mask  = (const float*)d_in[4];
    const int*   res_idx    = (const int*)d_in[5];
    const float* Bm         = (const float*)d_in[6];
    const float* Wq         = (const float*)d_in[7];
    const float* Wk         = (const float*)d_in[8];
    const float* Wv         = (const float*)d_in[9];
    const float* ln_g       = (const float*)d_in[10];
    const float* ln_b       = (const float*)d_in[11];

    float* ws = (float*)d_ws;
    const size_t OFF_LOG = 0;                          // logits 4,194,304
    const size_t OFF_Q0  = OFF_LOG + (size_t)NB*NN*NK; // q0     3,145,728
    const size_t OFF_KM  = OFF_Q0  + (size_t)NB*NN*NC; // kmat     393,216 (later: pmax/knn/occ)
    const size_t OFF_V   = OFF_KM  + (size_t)NB*NK*NC; // vmat     393,216
    const size_t OFF_GT  = OFF_V   + (size_t)NB*NK*NC; // Gt       393,216
    const size_t OFF_LS  = OFF_GT  + (size_t)NB*NK*NC; // Lsum (16)
    const size_t OFF_LP  = OFF_LS  + 16;               // loss partials (512)

    float* logits = ws + OFF_LOG;
    float* q0     = ws + OFF_Q0;
    float* kmat   = ws + OFF_KM;
    float* vmat   = ws + OFF_V;
    float* Gt     = ws + OFF_GT;
    float* Lsum   = ws + OFF_LS;
    float* lpart  = ws + OFF_LP;
    // aliases into the kmat region (kmat dead after k_gemm384_bt):
    float* pmaxv    = ws + OFF_KM;                     //  65,536
    int*   pmaxi    = (int*)(ws + OFF_KM +  65536);    //  65,536
    int*   knn      = (int*)(ws + OFF_KM + 131072);    //  16,384
    float* occ_part = ws + OFF_KM + 147456;            //  65,536 (total 213,  < 393,216)

    float* out      = (float*)d_out;
    float* out_s0   = out;
    float* out_mu0  = out      + (size_t)NB*NN*NC;
    float* out_Sig0 = out_mu0  + (size_t)NB*NN*3;
    float* out_Bl   = out_Sig0 + (size_t)NB*NN*9;
    float* out_occn = out_Bl   + (size_t)NB*NN*NR;
    float* out_loss = out_occn + (size_t)NB*NK;

    (void)in_sizes; (void)n_in; (void)out_size; (void)ws_size;

    k_masksum<<<NB, 256, 0, stream>>>(node_mask, Lsum);
    k_q0<<<NB*NN, 128, 0, stream>>>(res_idx, node_mask, Bm, ln_g, ln_b, Lsum, q0);
    k_gemm384<<<dim3((NB*NK)/64, NC/64), 256, 0, stream>>>(s_parent, Wk, kmat);
    k_gemm384<<<dim3((NB*NK)/64, NC/64), 256, 0, stream>>>(s_parent, Wv, vmat);
    k_gemm384_bt<<<dim3((NB*NK)/64, NC/64), 256, 0, stream>>>(kmat, Wq, Gt);  // Gt[p][d]
    // kmat dead from here; its region is reused for pmax/knn/occ
    k_score_topk<<<NB*NK, 256, 0, stream>>>(mu_parent, Sig_parent, mask_par, knn);
    k_logits_mfma<<<512, 256, 0, stream>>>(q0, Gt, mask_par, logits, pmaxv, pmaxi);
    hipMemsetAsync(occ_part, 0, (size_t)NSLICE*NB*NK*sizeof(float), stream);
    k_final<<<(NB*NN)/16, 256, 0, stream>>>(logits, vmat, mu_parent, Sig_parent, node_mask,
                                            pmaxv, pmaxi, knn, out_s0, out_mu0, out_Sig0,
                                            out_Bl, occ_part, lpart);
    k_finalize<<<1, 1024, 0, stream>>>(occ_part, Lsum, lpart, out_occn, out_loss);
}

// Round 5
// 164.750 us; speedup vs baseline: 2.0742x; 1.0162x over previous
//
#include <hip/hip_runtime.h>
#include <math.h>

#define NB 2
#define NN 4096
#define NK 512
#define NC 384
#define NR 16
#define NCH 192
#define NSLICE 64

static constexpr float INV_SQRT_C = 0.051031036307982884f; // 1/sqrt(384)
static constexpr float TWO_PI     = 6.283185307179586f;
static constexpr float F_JITTER   = 1e-4f;

typedef __attribute__((ext_vector_type(8))) short short8;
typedef __attribute__((ext_vector_type(4))) float f32x4;
typedef __attribute__((ext_vector_type(4))) unsigned short us4;

__device__ __forceinline__ void split3(float x, unsigned short& h, unsigned short& m_, unsigned short& l_) {
    unsigned int xi = __float_as_uint(x);
    unsigned int uh = (xi + 0x7fffu + ((xi >> 16) & 1u)) >> 16;
    float fh = __uint_as_float(uh << 16);
    float r  = x - fh;                      // exact (<=16 significant bits)
    unsigned int ri = __float_as_uint(r);
    unsigned int um = (ri + 0x7fffu + ((ri >> 16) & 1u)) >> 16;
    float fm = __uint_as_float(um << 16);
    float r2 = r - fm;                      // exact (<=8 significant bits)
    unsigned int r2i = __float_as_uint(r2);
    unsigned int ul = (r2i + 0x7fffu + ((r2i >> 16) & 1u)) >> 16;
    h = (unsigned short)uh; m_ = (unsigned short)um; l_ = (unsigned short)ul;
}

// ---------------- kernel 1: per-batch node_mask sum ----------------
__global__ __launch_bounds__(256) void k_masksum(const float* __restrict__ node_mask,
                                                 float* __restrict__ Lsum) {
    int b = blockIdx.x, t = threadIdx.x;
    __shared__ float red[256];
    float s = 0.f;
    for (int n = t; n < NN; n += 256) s += node_mask[b*NN + n];
    red[t] = s; __syncthreads();
    for (int w = 128; w > 0; w >>= 1) { if (t < w) red[t] += red[t+w]; __syncthreads(); }
    if (t == 0) Lsum[b] = red[0];
}

// ---------------- kernel 2: fourier emb + layernorm -> q0 ----------------
__global__ __launch_bounds__(128) void k_q0(const int* __restrict__ res_idx,
                                            const float* __restrict__ node_mask,
                                            const float* __restrict__ Bm,
                                            const float* __restrict__ ln_g,
                                            const float* __restrict__ ln_b,
                                            const float* __restrict__ Lsum,
                                            float* __restrict__ q0) {
    int row = blockIdx.x, t = threadIdx.x;
    int b = row >> 12;
    __shared__ float emb[NC];
    __shared__ float red[128];
    float m = node_mask[row];
    float Lb = fmaxf(Lsum[b], 1.0f);
    float denom = fmaxf(Lb - 1.0f, 1.0f);
    int ri = res_idx[row];
    ri = ri < 0 ? 0 : (ri > 4095 ? 4095 : ri);
    float pos = fminf(fmaxf((float)ri / denom, 0.f), 1.f);
    for (int i = t; i < NCH; i += 128) {
        float pr = TWO_PI * pos * Bm[i];
        emb[i]      = cosf(pr) * m;
        emb[i+NCH]  = sinf(pr) * m;
    }
    __syncthreads();
    float e0 = emb[t], e1 = emb[t+128], e2 = emb[t+256];
    red[t] = e0 + e1 + e2; __syncthreads();
    for (int w = 64; w > 0; w >>= 1) { if (t < w) red[t] += red[t+w]; __syncthreads(); }
    float mean = red[0] * (1.0f/NC);
    __syncthreads();
    float d0 = e0-mean, d1 = e1-mean, d2 = e2-mean;
    red[t] = d0*d0 + d1*d1 + d2*d2; __syncthreads();
    for (int w = 64; w > 0; w >>= 1) { if (t < w) red[t] += red[t+w]; __syncthreads(); }
    float var = red[0] * (1.0f/NC);
    float inv = 1.0f / sqrtf(var + 1e-5f);
    q0[(size_t)row*NC + t]       = d0*inv*ln_g[t]      + ln_b[t];
    q0[(size_t)row*NC + t + 128] = d1*inv*ln_g[t+128]  + ln_b[t+128];
    q0[(size_t)row*NC + t + 256] = d2*inv*ln_g[t+256]  + ln_b[t+256];
}

// ---------------- kernel 3: [M,384]@[384,384] fp32 GEMM (B row-major) ----------------
__global__ __launch_bounds__(256) void k_gemm384(const float* __restrict__ A,
                                                 const float* __restrict__ W,
                                                 float* __restrict__ out) {
    __shared__ float As[16][68];
    __shared__ float Ws[16][68];
    int t = threadIdx.x;
    int tx = t & 15, ty = t >> 4;
    int rowbase = blockIdx.x * 64, colbase = blockIdx.y * 64;
    float acc[4][4] = {};
    for (int k0 = 0; k0 < NC; k0 += 16) {
        {
            int r = t >> 2, ja = (t & 3) << 2;
            float4 a4 = *(const float4*)(A + (size_t)(rowbase + r)*NC + k0 + ja);
            As[ja+0][r] = a4.x; As[ja+1][r] = a4.y; As[ja+2][r] = a4.z; As[ja+3][r] = a4.w;
        }
        {
            int kr = t >> 4, jw = (t & 15) << 2;
            float4 w4 = *(const float4*)(W + (size_t)(k0 + kr)*NC + colbase + jw);
            *(float4*)&Ws[kr][jw] = w4;
        }
        __syncthreads();
        #pragma unroll
        for (int kk = 0; kk < 16; ++kk) {
            float4 av = *(const float4*)&As[kk][ty<<2];
            float4 wv = *(const float4*)&Ws[kk][tx<<2];
            float aa[4] = {av.x, av.y, av.z, av.w};
            float ww[4] = {wv.x, wv.y, wv.z, wv.w};
            #pragma unroll
            for (int i = 0; i < 4; ++i)
                #pragma unroll
                for (int j = 0; j < 4; ++j)
                    acc[i][j] += aa[i]*ww[j];
        }
        __syncthreads();
    }
    #pragma unroll
    for (int i = 0; i < 4; ++i) {
        float4 o = make_float4(acc[i][0], acc[i][1], acc[i][2], acc[i][3]);
        *(float4*)(out + (size_t)(rowbase + (ty<<2) + i)*NC + colbase + (tx<<2)) = o;
    }
}

// -------- kernel 3b: out[m][n] = sum_k A[m][k]*B[n][k]  (B^T GEMM, for G^t = k @ Wq^T) --------
__global__ __launch_bounds__(256) void k_gemm384_bt(const float* __restrict__ A,
                                                    const float* __restrict__ Bt,
                                                    float* __restrict__ out) {
    __shared__ float As[16][68];
    __shared__ float Ws[16][68];
    int t = threadIdx.x;
    int tx = t & 15, ty = t >> 4;
    int rowbase = blockIdx.x * 64, colbase = blockIdx.y * 64;
    float acc[4][4] = {};
    for (int k0 = 0; k0 < NC; k0 += 16) {
        {
            int r = t >> 2, ja = (t & 3) << 2;
            float4 a4 = *(const float4*)(A + (size_t)(rowbase + r)*NC + k0 + ja);
            As[ja+0][r] = a4.x; As[ja+1][r] = a4.y; As[ja+2][r] = a4.z; As[ja+3][r] = a4.w;
        }
        {
            int r = t >> 2, jb = (t & 3) << 2;
            float4 b4 = *(const float4*)(Bt + (size_t)(colbase + r)*NC + k0 + jb);
            Ws[jb+0][r] = b4.x; Ws[jb+1][r] = b4.y; Ws[jb+2][r] = b4.z; Ws[jb+3][r] = b4.w;
        }
        __syncthreads();
        #pragma unroll
        for (int kk = 0; kk < 16; ++kk) {
            float4 av = *(const float4*)&As[kk][ty<<2];
            float4 wv = *(const float4*)&Ws[kk][tx<<2];
            float aa[4] = {av.x, av.y, av.z, av.w};
            float ww[4] = {wv.x, wv.y, wv.z, wv.w};
            #pragma unroll
            for (int i = 0; i < 4; ++i)
                #pragma unroll
                for (int j = 0; j < 4; ++j)
                    acc[i][j] += aa[i]*ww[j];
        }
        __syncthreads();
    }
    #pragma unroll
    for (int i = 0; i < 4; ++i) {
        float4 o = make_float4(acc[i][0], acc[i][1], acc[i][2], acc[i][3]);
        *(float4*)(out + (size_t)(rowbase + (ty<<2) + i)*NC + colbase + (tx<<2)) = o;
    }
}

// ---------------- kernel 4: K x K overlap scores + top-16 per row ----------------
__global__ __launch_bounds__(256) void k_score_topk(const float* __restrict__ mu,
                                                    const float* __restrict__ Sg,
                                                    const float* __restrict__ maskp,
                                                    int* __restrict__ knn) {
    int b = blockIdx.x >> 9, i = blockIdx.x & 511;
    int t = threadIdx.x;
    __shared__ float swv[4];
    __shared__ int   swi[4];
    __shared__ int   winner;
    const float* mui = mu + (size_t)(b*NK + i)*3;
    const float* Sgi = Sg + (size_t)(b*NK + i)*9;
    float mi0 = mui[0], mi1 = mui[1], mi2 = mui[2];
    float S0 = Sgi[0], S1 = Sgi[1], S2 = Sgi[2], S4 = Sgi[4], S5 = Sgi[5], S8 = Sgi[8];
    float mski = maskp[b*NK + i];
    float cand[2];
    #pragma unroll
    for (int h = 0; h < 2; ++h) {
        int j = t + h*256;
        const float* muj = mu + (size_t)(b*NK + j)*3;
        const float* Sgj = Sg + (size_t)(b*NK + j)*9;
        float d0 = mi0-muj[0], d1 = mi1-muj[1], d2 = mi2-muj[2];
        float a00 = S0+Sgj[0]+1e-6f, a01 = S1+Sgj[1],       a02 = S2+Sgj[2];
        float a11 = S4+Sgj[4]+1e-6f, a12 = S5+Sgj[5],       a22 = S8+Sgj[8]+1e-6f;
        float c00 = a11*a22 - a12*a12;
        float c01 = a02*a12 - a01*a22;
        float c02 = a01*a12 - a02*a11;
        float c11 = a00*a22 - a02*a02;
        float c12 = a01*a02 - a00*a12;
        float c22 = a00*a11 - a01*a01;
        float det = a00*c00 + a01*c01 + a02*c02;
        float t0 = c00*d0 + c01*d1 + c02*d2;
        float t1 = c01*d0 + c11*d1 + c12*d2;
        float t2 = c02*d0 + c12*d1 + c22*d2;
        float maha = (d0*t0 + d1*t1 + d2*t2) / det;
        float score = -0.5f*(maha + logf(det));
        float mj = maskp[b*NK + j];
        cand[h] = (mski*mj < 0.5f) ? -1e9f : score;
    }
    int lane = t & 63, wv = t >> 6;
    for (int it = 0; it < NR; ++it) {
        float bv; int bi;
        if (cand[0] >= cand[1]) { bv = cand[0]; bi = t; }
        else                    { bv = cand[1]; bi = t + 256; }
        #pragma unroll
        for (int off = 32; off > 0; off >>= 1) {
            float v2 = __shfl_xor(bv, off);
            int   i2 = __shfl_xor(bi, off);
            if (v2 > bv || (v2 == bv && i2 < bi)) { bv = v2; bi = i2; }
        }
        if (lane == 0) { swv[wv] = bv; swi[wv] = bi; }
        __syncthreads();
        if (t == 0) {
            float B = swv[0]; int I = swi[0];
            #pragma unroll
            for (int w = 1; w < 4; ++w)
                if (swv[w] > B || (swv[w] == B && swi[w] < I)) { B = swv[w]; I = swi[w]; }
            knn[((size_t)(b*NK + i))*NR + it] = I;
            winner = I;
        }
        __syncthreads();
        int wn = winner;
        if (t == wn)        cand[0] = -INFINITY;
        if (t + 256 == wn)  cand[1] = -INFINITY;
    }
}

// -------- kernel 5: logits = q0 @ Gt^T via MFMA 3-split bf16 (6 passes) + argmax partials --------
// also zeroes occ_part (replaces graph-captured hipMemsetAsync, which ran at 6.9 GB/s)
__global__ __launch_bounds__(256) void k_logits_mfma(const float* __restrict__ q0,
                                                     const float* __restrict__ Gt,
                                                     const float* __restrict__ maskp,
                                                     float* __restrict__ logits,
                                                     float* __restrict__ pmaxv,
                                                     int*   __restrict__ pmaxi,
                                                     float* __restrict__ occ_part) {
    int bid = blockIdx.x;
    {   // zero occ_part [NSLICE][NB*NK] = 65536 floats across 512x256 threads
        int gid = bid * 256 + threadIdx.x;
        if (gid < NSLICE*NB*NK) occ_part[gid] = 0.f;
    }
    int wg = (bid & 7) * 64 + (bid >> 3);      // XCD-chunked swizzle (512 = 8*64)
    int b  = wg >> 8;
    int r8 = (wg >> 3) & 31;
    int cb = wg & 7;
    int rowbase = r8 << 7;
    int colbase = cb << 6;

    __shared__ __align__(16) unsigned short Ah[128][40];
    __shared__ __align__(16) unsigned short Am[128][40];
    __shared__ __align__(16) unsigned short Al[128][40];
    __shared__ __align__(16) unsigned short Bh[64][40];
    __shared__ __align__(16) unsigned short Bm2[64][40];
    __shared__ __align__(16) unsigned short Bl[64][40];
    __shared__ float rmv[128][2];
    __shared__ int   rmi[128][2];

    int t = threadIdx.x;
    int lane = t & 63, wv = t >> 6;
    int wr = wv >> 1, wc = wv & 1;
    int a = lane & 15, g = lane >> 4;

    const float* Ag = q0 + ((size_t)(b << 12) + rowbase) * NC;
    const float* Bg = Gt + ((size_t)(b << 9) + colbase) * NC;

    f32x4 acc[4][2];
    #pragma unroll
    for (int i = 0; i < 4; ++i)
        #pragma unroll
        for (int j = 0; j < 2; ++j)
            acc[i][j] = (f32x4){0.f, 0.f, 0.f, 0.f};

    for (int k0 = 0; k0 < NC; k0 += 32) {
        __syncthreads();
        #pragma unroll
        for (int i = 0; i < 4; ++i) {           // A: 128 rows x 32 f32 = 1024 float4
            int id = i*256 + t;
            int row = id >> 3, seg = id & 7;
            float4 v = *(const float4*)(Ag + (size_t)row*NC + k0 + (seg << 2));
            unsigned short h0,m0,l0,h1,m1,l1,h2,m2,l2,h3,m3,l3;
            split3(v.x, h0, m0, l0); split3(v.y, h1, m1, l1);
            split3(v.z, h2, m2, l2); split3(v.w, h3, m3, l3);
            *(us4*)&Ah[row][seg << 2] = (us4){h0, h1, h2, h3};
            *(us4*)&Am[row][seg << 2] = (us4){m0, m1, m2, m3};
            *(us4*)&Al[row][seg << 2] = (us4){l0, l1, l2, l3};
        }
        #pragma unroll
        for (int i = 0; i < 2; ++i) {           // B: 64 rows x 32 f32 = 512 float4
            int id = i*256 + t;
            int row = id >> 3, seg = id & 7;
            float4 v = *(const float4*)(Bg + (size_t)row*NC + k0 + (seg << 2));
            unsigned short h0,m0,l0,h1,m1,l1,h2,m2,l2,h3,m3,l3;
            split3(v.x, h0, m0, l0); split3(v.y, h1, m1, l1);
            split3(v.z, h2, m2, l2); split3(v.w, h3, m3, l3);
            *(us4*)&Bh[row][seg << 2]  = (us4){h0, h1, h2, h3};
            *(us4*)&Bm2[row][seg << 2] = (us4){m0, m1, m2, m3};
            *(us4*)&Bl[row][seg << 2]  = (us4){l0, l1, l2, l3};
        }
        __syncthreads();
        short8 afh[4], afm[4], afl[4];
        #pragma unroll
        for (int fr = 0; fr < 4; ++fr) {
            int r = (wr << 6) + (fr << 4) + a;
            afh[fr] = *(const short8*)&Ah[r][g << 3];
            afm[fr] = *(const short8*)&Am[r][g << 3];
            afl[fr] = *(const short8*)&Al[r][g << 3];
        }
        #pragma unroll
        for (int fc = 0; fc < 2; ++fc) {
            int c = (wc << 5) + (fc << 4) + a;
            short8 bh = *(const short8*)&Bh[c][g << 3];
            short8 bm = *(const short8*)&Bm2[c][g << 3];
            short8 bl = *(const short8*)&Bl[c][g << 3];
            #pragma unroll
            for (int fr = 0; fr < 4; ++fr) {
                acc[fr][fc] = __builtin_amdgcn_mfma_f32_16x16x32_bf16(afh[fr], bh, acc[fr][fc], 0, 0, 0);
                acc[fr][fc] = __builtin_amdgcn_mfma_f32_16x16x32_bf16(afh[fr], bm, acc[fr][fc], 0, 0, 0);
                acc[fr][fc] = __builtin_amdgcn_mfma_f32_16x16x32_bf16(afm[fr], bh, acc[fr][fc], 0, 0, 0);
                acc[fr][fc] = __builtin_amdgcn_mfma_f32_16x16x32_bf16(afh[fr], bl, acc[fr][fc], 0, 0, 0);
                acc[fr][fc] = __builtin_amdgcn_mfma_f32_16x16x32_bf16(afl[fr], bh, acc[fr][fc], 0, 0, 0);
                acc[fr][fc] = __builtin_amdgcn_mfma_f32_16x16x32_bf16(afm[fr], bm, acc[fr][fc], 0, 0, 0);
            }
        }
    }
    // epilogue: scale, store logits, masked per-row argmax partial
    float mk[2];
    #pragma unroll
    for (int fc = 0; fc < 2; ++fc)
        mk[fc] = (maskp[(b << 9) + colbase + (wc << 5) + (fc << 4) + a] - 1.0f) * 1e9f;
    int colg0 = colbase + (wc << 5) + a;
    #pragma unroll
    for (int fr = 0; fr < 4; ++fr) {
        #pragma unroll
        for (int reg = 0; reg < 4; ++reg) {
            int rloc = (wr << 6) + (fr << 4) + (g << 2) + reg;
            size_t rowg = (size_t)(b << 12) + rowbase + rloc;
            float v0 = acc[fr][0][reg] * INV_SQRT_C;
            float v1 = acc[fr][1][reg] * INV_SQRT_C;
            logits[rowg * NK + colg0]      = v0;
            logits[rowg * NK + colg0 + 16] = v1;
            float bv = v0 + mk[0]; int bc = colg0;
            float w1 = v1 + mk[1];
            if (w1 > bv) { bv = w1; bc = colg0 + 16; }
            #pragma unroll
            for (int off = 1; off < 16; off <<= 1) {
                float v2 = __shfl_xor(bv, off);
                int   c2 = __shfl_xor(bc, off);
                if (v2 > bv || (v2 == bv && c2 < bc)) { bv = v2; bc = c2; }
            }
            if (a == 0) { rmv[rloc][wc] = bv; rmi[rloc][wc] = bc; }
        }
    }
    __syncthreads();
    if (t < 128) {
        float v0 = rmv[t][0], v1 = rmv[t][1];
        int   c0 = rmi[t][0], c1 = rmi[t][1];
        float bv = v0; int bc = c0;
        if (v1 > bv) { bv = v1; bc = c1; }     // wc=1 cols are larger: strict >
        pmaxv[(((size_t)(b << 3) + cb) << 12) + rowbase + t] = bv;
        pmaxi[(((size_t)(b << 3) + cb) << 12) + rowbase + t] = bc;
    }
}

// ---------------- kernel 6: gathered attention epilogue — 16 rows/block ----------------
__global__ __launch_bounds__(256) void k_final(const float* __restrict__ logits,
                                               const float* __restrict__ vmat,
                                               const float* __restrict__ mu,
                                               const float* __restrict__ Sg,
                                               const float* __restrict__ node_mask,
                                               const float* __restrict__ pmaxv,
                                               const int*   __restrict__ pmaxi,
                                               const int* __restrict__ knn,
                                               float* __restrict__ out_s0,
                                               float* __restrict__ out_mu0,
                                               float* __restrict__ out_Sig0,
                                               float* __restrict__ out_Bl,
                                               float* __restrict__ occ_part,
                                               float* __restrict__ loss_part) {
    int t = threadIdx.x;
    int rowbase = blockIdx.x << 4;
    int b = rowbase >> 12;
    int l  = t & 63;
    int sub = l >> 4, ll = l & 15;
    int r = ((t >> 6) << 2) + sub;          // 0..15, this thread's row
    int grow = rowbase + r;
    __shared__ float wl[16][17];
    __shared__ int   pidx[16][17];
    __shared__ float lred[16];
    __shared__ float msk[16];
    __shared__ int   j0s[16];

    if (t < 16) {                            // combine 8 argmax partials -> j0
        int rowb = (rowbase & 4095) + t;
        float bv = -INFINITY; int bj = 0;
        #pragma unroll
        for (int cbk = 0; cbk < 8; ++cbk) {
            size_t idx = (((size_t)(b << 3) + cbk) << 12) + rowb;
            float v = pmaxv[idx];
            if (v > bv) { bv = v; bj = pmaxi[idx]; }
        }
        j0s[t] = bj;
    }
    __syncthreads();

    float m = node_mask[grow];
    int p = knn[((size_t)(b*NK + j0s[r]))*NR + ll];
    float v = logits[(size_t)grow*NK + p];
    float mx = v;
    #pragma unroll
    for (int off = 8; off > 0; off >>= 1) mx = fmaxf(mx, __shfl_xor(mx, off));
    float e = expf(v - mx);
    float sme = e;
    #pragma unroll
    for (int off = 8; off > 0; off >>= 1) sme += __shfl_xor(sme, off);
    float w = e / sme;
    wl[r][ll] = w;
    pidx[r][ll] = p;
    out_Bl[(size_t)rowbase*NR + t] = w;     // r*16+ll == t

    const float* mur = mu + (size_t)(b*NK + p)*3;
    const float* Sgr = Sg + (size_t)(b*NK + p)*9;
    float mr0 = mur[0], mr1 = mur[1], mr2 = mur[2];
    float m0 = w*mr0, m1 = w*mr1, m2 = w*mr2;
    #pragma unroll
    for (int off = 8; off > 0; off >>= 1) {
        m0 += __shfl_xor(m0, off); m1 += __shfl_xor(m1, off); m2 += __shfl_xor(m2, off);
    }
    float d0 = mr0-m0, d1 = mr1-m1, d2 = mr2-m2;
    float a00 = Sgr[0], a01 = Sgr[1], a02 = Sgr[2];
    float a11 = Sgr[4], a12 = Sgr[5], a22 = Sgr[8];
    float p00 = w*(a00 + d0*d0), p01 = w*(a01 + d0*d1), p02 = w*(a02 + d0*d2);
    float p11 = w*(a11 + d1*d1), p12 = w*(a12 + d1*d2), p22 = w*(a22 + d2*d2);
    #pragma unroll
    for (int off = 8; off > 0; off >>= 1) {
        p00 += __shfl_xor(p00, off); p01 += __shfl_xor(p01, off); p02 += __shfl_xor(p02, off);
        p11 += __shfl_xor(p11, off); p12 += __shfl_xor(p12, off); p22 += __shfl_xor(p22, off);
    }
    float c00 = a11*a22 - a12*a12;
    float c01 = a02*a12 - a01*a22;
    float c02 = a01*a12 - a02*a11;
    float c11 = a00*a22 - a02*a02;
    float c12 = a01*a02 - a00*a12;
    float c22 = a00*a11 - a01*a01;
    float det = a00*c00 + a01*c01 + a02*c02;
    float t0 = c00*d0 + c01*d1 + c02*d2;
    float t1 = c01*d0 + c11*d1 + c12*d2;
    float t2 = c02*d0 + c12*d1 + c22*d2;
    float maha = (d0*t0 + d1*t1 + d2*t2) / det;
    float score = -0.5f*(maha + logf(det));
    float lp = w*score;
    #pragma unroll
    for (int off = 8; off > 0; off >>= 1) lp += __shfl_xor(lp, off);
    if (ll == 0) {
        out_mu0[(size_t)grow*3+0] = m0;
        out_mu0[(size_t)grow*3+1] = m1;
        out_mu0[(size_t)grow*3+2] = m2;
        float* o = out_Sig0 + (size_t)grow*9;
        o[0]=p00+F_JITTER; o[1]=p01;          o[2]=p02;
        o[3]=p01;          o[4]=p11+F_JITTER; o[5]=p12;
        o[6]=p02;          o[7]=p12;          o[8]=p22+F_JITTER;
        lred[r] = m*lp;
        msk[r] = m;
    }
    atomicAdd(&occ_part[(size_t)(blockIdx.x & (NSLICE-1))*(NB*NK) + b*NK + p], w*m);
    __syncthreads();
    if (t == 0) {
        float s = 0.f;
        #pragma unroll
        for (int i = 0; i < 16; ++i) s += lred[i];
        loss_part[blockIdx.x] = s;
    }
    const float4* vb = (const float4*)(vmat + (size_t)b*NK*NC);
    #pragma unroll
    for (int it = 0; it < 6; ++it) {
        int id = it*256 + t;
        int row = id / 96;
        int col = id - row*96;
        float4 acc4 = make_float4(0.f, 0.f, 0.f, 0.f);
        #pragma unroll
        for (int r2 = 0; r2 < NR; ++r2) {
            float ww = wl[row][r2];
            float4 vv = vb[(size_t)pidx[row][r2]*96 + col];
            acc4.x += ww*vv.x; acc4.y += ww*vv.y; acc4.z += ww*vv.z; acc4.w += ww*vv.w;
        }
        float mm = msk[row];
        acc4.x *= mm; acc4.y *= mm; acc4.z *= mm; acc4.w *= mm;
        ((float4*)(out_s0 + (size_t)(rowbase + row)*NC))[col] = acc4;
    }
}

// ---------------- kernel 7: occ-slice reduce + normalize + loss ----------------
__global__ __launch_bounds__(1024) void k_finalize(const float* __restrict__ occ_part,
                                                   const float* __restrict__ Lsum,
                                                   const float* __restrict__ loss_part,
                                                   float* __restrict__ out_occn,
                                                   float* __restrict__ out_loss) {
    int t = threadIdx.x;
    __shared__ float red[1024];
    float s = 0.f;
    for (int sl = 0; sl < NSLICE; ++sl) s += occ_part[(size_t)sl*(NB*NK) + t];
    red[t] = s; __syncthreads();
    for (int w = 256; w > 0; w >>= 1) {
        if ((t & 511) < w) red[t] += red[t+w];
        __syncthreads();
    }
    float tot = red[t & 512];
    float occn = s / fmaxf(tot, 1e-9f);
    __syncthreads();
    out_occn[t] = occn;
    float lp = (t < 512) ? loss_part[t] : 0.f;
    red[t] = lp; __syncthreads();
    for (int w = 512; w > 0; w >>= 1) {
        if (t < w) red[t] += red[t+w];
        __syncthreads();
    }
    if (t == 0) {
        float dnm = fmaxf(Lsum[0] + Lsum[1], 1.0f);
        out_loss[0] = -(red[0] / dnm);
    }
}

extern "C" void kernel_launch(void* const* d_in, const int* in_sizes, int n_in,
                              void* d_out, int out_size, void* d_ws, size_t ws_size,
                              hipStream_t stream) {
    const float* s_parent   = (const float*)d_in[0];
    const float* mu_parent  = (const float*)d_in[1];
    const float* Sig_parent = (const float*)d_in[2];
    const float* mask_par   = (const float*)d_in[3];
    const float* node_mask  = (const float*)d_in[4];
    const int*   res_idx    = (const int*)d_in[5];
    const float* Bm         = (const float*)d_in[6];
    const float* Wq         = (const float*)d_in[7];
    const float* Wk         = (const float*)d_in[8];
    const float* Wv         = (const float*)d_in[9];
    const float* ln_g       = (const float*)d_in[10];
    const float* ln_b       = (const float*)d_in[11];

    float* ws = (float*)d_ws;
    const size_t OFF_LOG = 0;                          // logits 4,194,304
    const size_t OFF_Q0  = OFF_LOG + (size_t)NB*NN*NK; // q0     3,145,728
    const size_t OFF_KM  = OFF_Q0  + (size_t)NB*NN*NC; // kmat     393,216 (later: pmax/knn/occ)
    const size_t OFF_V   = OFF_KM  + (size_t)NB*NK*NC; // vmat     393,216
    const size_t OFF_GT  = OFF_V   + (size_t)NB*NK*NC; // Gt       393,216
    const size_t OFF_LS  = OFF_GT  + (size_t)NB*NK*NC; // Lsum (16)
    const size_t OFF_LP  = OFF_LS  + 16;               // loss partials (512)

    float* logits = ws + OFF_LOG;
    float* q0     = ws + OFF_Q0;
    float* kmat   = ws + OFF_KM;
    float* vmat   = ws + OFF_V;
    float* Gt     = ws + OFF_GT;
    float* Lsum   = ws + OFF_LS;
    float* lpart  = ws + OFF_LP;
    // aliases into the kmat region (kmat dead after k_gemm384_bt):
    float* pmaxv    = ws + OFF_KM;                     //  65,536
    int*   pmaxi    = (int*)(ws + OFF_KM +  65536);    //  65,536
    int*   knn      = (int*)(ws + OFF_KM + 131072);    //  16,384
    float* occ_part = ws + OFF_KM + 147456;            //  65,536 floats

    float* out      = (float*)d_out;
    float* out_s0   = out;
    float* out_mu0  = out      + (size_t)NB*NN*NC;
    float* out_Sig0 = out_mu0  + (size_t)NB*NN*3;
    float* out_Bl   = out_Sig0 + (size_t)NB*NN*9;
    float* out_occn = out_Bl   + (size_t)NB*NN*NR;
    float* out_loss = out_occn + (size_t)NB*NK;

    (void)in_sizes; (void)n_in; (void)out_size; (void)ws_size;

    k_masksum<<<NB, 256, 0, stream>>>(node_mask, Lsum);
    k_q0<<<NB*NN, 128, 0, stream>>>(res_idx, node_mask, Bm, ln_g, ln_b, Lsum, q0);
    k_gemm384<<<dim3((NB*NK)/64, NC/64), 256, 0, stream>>>(s_parent, Wk, kmat);
    k_gemm384<<<dim3((NB*NK)/64, NC/64), 256, 0, stream>>>(s_parent, Wv, vmat);
    k_gemm384_bt<<<dim3((NB*NK)/64, NC/64), 256, 0, stream>>>(kmat, Wq, Gt);  // Gt[p][d]
    // kmat dead from here; its region is reused for pmax/knn/occ
    k_score_topk<<<NB*NK, 256, 0, stream>>>(mu_parent, Sig_parent, mask_par, knn);
    k_logits_mfma<<<512, 256, 0, stream>>>(q0, Gt, mask_par, logits, pmaxv, pmaxi, occ_part);
    k_final<<<(NB*NN)/16, 256, 0, stream>>>(logits, vmat, mu_parent, Sig_parent, node_mask,
                                            pmaxv, pmaxi, knn, out_s0, out_mu0, out_Sig0,
                                            out_Bl, occ_part, lpart);
    k_finalize<<<1, 1024, 0, stream>>>(occ_part, Lsum, lpart, out_occn, out_loss);
}

// Round 6
// 139.458 us; speedup vs baseline: 2.4504x; 1.1814x over previous
//
#include <hip/hip_runtime.h>
#include <math.h>

#define NB 2
#define NN 4096
#define NK 512
#define NC 384
#define NR 16
#define NCH 192
#define NSLICE 64

static constexpr float INV_SQRT_C = 0.051031036307982884f; // 1/sqrt(384)
static constexpr float TWO_PI     = 6.283185307179586f;
static constexpr float F_JITTER   = 1e-4f;

typedef __attribute__((ext_vector_type(8))) short short8;
typedef __attribute__((ext_vector_type(4))) float f32x4;
typedef __attribute__((ext_vector_type(4))) unsigned short us4;

__device__ __forceinline__ void split3(float x, unsigned short& h, unsigned short& m_, unsigned short& l_) {
    unsigned int xi = __float_as_uint(x);
    unsigned int uh = (xi + 0x7fffu + ((xi >> 16) & 1u)) >> 16;
    float fh = __uint_as_float(uh << 16);
    float r  = x - fh;                      // exact (<=16 significant bits)
    unsigned int ri = __float_as_uint(r);
    unsigned int um = (ri + 0x7fffu + ((ri >> 16) & 1u)) >> 16;
    float fm = __uint_as_float(um << 16);
    float r2 = r - fm;                      // exact (<=8 significant bits)
    unsigned int r2i = __float_as_uint(r2);
    unsigned int ul = (r2i + 0x7fffu + ((r2i >> 16) & 1u)) >> 16;
    h = (unsigned short)uh; m_ = (unsigned short)um; l_ = (unsigned short)ul;
}

// ---------------- kernel 1: per-batch node_mask sum ----------------
__global__ __launch_bounds__(256) void k_masksum(const float* __restrict__ node_mask,
                                                 float* __restrict__ Lsum) {
    int b = blockIdx.x, t = threadIdx.x;
    __shared__ float red[256];
    float s = 0.f;
    for (int n = t; n < NN; n += 256) s += node_mask[b*NN + n];
    red[t] = s; __syncthreads();
    for (int w = 128; w > 0; w >>= 1) { if (t < w) red[t] += red[t+w]; __syncthreads(); }
    if (t == 0) Lsum[b] = red[0];
}

// ------- kernel 2: fourier emb + layernorm -> q0 (wave-per-row, no barriers) -------
template<bool SPLIT>
__global__ __launch_bounds__(256) void k_q0(const int* __restrict__ res_idx,
                                            const float* __restrict__ node_mask,
                                            const float* __restrict__ Bm,
                                            const float* __restrict__ ln_g,
                                            const float* __restrict__ ln_b,
                                            const float* __restrict__ Lsum,
                                            float* __restrict__ q0f,
                                            unsigned short* __restrict__ qh,
                                            unsigned short* __restrict__ qm,
                                            unsigned short* __restrict__ ql) {
    int w = threadIdx.x >> 6, l = threadIdx.x & 63;
    int row = (blockIdx.x << 2) + w;
    int b = row >> 12;
    float m = node_mask[row];
    float Lb = fmaxf(Lsum[b], 1.0f);
    float denom = fmaxf(Lb - 1.0f, 1.0f);
    int ri = res_idx[row];
    ri = ri < 0 ? 0 : (ri > 4095 ? 4095 : ri);
    float pos = fminf(fmaxf((float)ri / denom, 0.f), 1.f);
    float v[6];
    #pragma unroll
    for (int j = 0; j < 3; ++j) {
        float pr = TWO_PI * pos * Bm[l + (j << 6)];
        v[j]   = cosf(pr) * m;
        v[j+3] = sinf(pr) * m;
    }
    float sum = v[0]+v[1]+v[2]+v[3]+v[4]+v[5];
    #pragma unroll
    for (int off = 32; off > 0; off >>= 1) sum += __shfl_xor(sum, off);
    float mean = sum * (1.0f/NC);
    float sq = 0.f;
    #pragma unroll
    for (int j = 0; j < 6; ++j) { v[j] -= mean; sq += v[j]*v[j]; }
    #pragma unroll
    for (int off = 32; off > 0; off >>= 1) sq += __shfl_xor(sq, off);
    float var = sq * (1.0f/NC);
    float inv = 1.0f / sqrtf(var + 1e-5f);
    #pragma unroll
    for (int j = 0; j < 6; ++j) {
        int p = l + (j << 6);
        float val = v[j]*inv*ln_g[p] + ln_b[p];
        size_t o = (size_t)row*NC + p;
        if constexpr (SPLIT) {
            unsigned short h, mm, ll;
            split3(val, h, mm, ll);
            qh[o] = h; qm[o] = mm; ql[o] = ll;
        } else {
            q0f[o] = val;
        }
    }
}

// -------- kernel 3: out[m][n] = sum_k A[m][k]*B[n][k]  (B^T GEMM: W2 = Wk @ Wq^T) --------
__global__ __launch_bounds__(256) void k_gemm384_bt(const float* __restrict__ A,
                                                    const float* __restrict__ Bt,
                                                    float* __restrict__ out) {
    __shared__ float As[16][68];
    __shared__ float Ws[16][68];
    int t = threadIdx.x;
    int tx = t & 15, ty = t >> 4;
    int rowbase = blockIdx.x * 64, colbase = blockIdx.y * 64;
    float acc[4][4] = {};
    for (int k0 = 0; k0 < NC; k0 += 16) {
        {
            int r = t >> 2, ja = (t & 3) << 2;
            float4 a4 = *(const float4*)(A + (size_t)(rowbase + r)*NC + k0 + ja);
            As[ja+0][r] = a4.x; As[ja+1][r] = a4.y; As[ja+2][r] = a4.z; As[ja+3][r] = a4.w;
        }
        {
            int r = t >> 2, jb = (t & 3) << 2;
            float4 b4 = *(const float4*)(Bt + (size_t)(colbase + r)*NC + k0 + jb);
            Ws[jb+0][r] = b4.x; Ws[jb+1][r] = b4.y; Ws[jb+2][r] = b4.z; Ws[jb+3][r] = b4.w;
        }
        __syncthreads();
        #pragma unroll
        for (int kk = 0; kk < 16; ++kk) {
            float4 av = *(const float4*)&As[kk][ty<<2];
            float4 wv = *(const float4*)&Ws[kk][tx<<2];
            float aa[4] = {av.x, av.y, av.z, av.w};
            float ww[4] = {wv.x, wv.y, wv.z, wv.w};
            #pragma unroll
            for (int i = 0; i < 4; ++i)
                #pragma unroll
                for (int j = 0; j < 4; ++j)
                    acc[i][j] += aa[i]*ww[j];
        }
        __syncthreads();
    }
    #pragma unroll
    for (int i = 0; i < 4; ++i) {
        float4 o = make_float4(acc[i][0], acc[i][1], acc[i][2], acc[i][3]);
        *(float4*)(out + (size_t)(rowbase + (ty<<2) + i)*NC + colbase + (tx<<2)) = o;
    }
}

// -------- kernel 3b: dual-z GEMM: z=0 -> vmat = s@Wv (fp32); z=1 -> Gt = s@W2 (fp32 or split) --------
template<bool SPLIT>
__global__ __launch_bounds__(256) void k_gemm_dualz(const float* __restrict__ A,
                                                    const float* __restrict__ Wv,
                                                    const float* __restrict__ W2,
                                                    float* __restrict__ vmat,
                                                    float* __restrict__ GtF,
                                                    unsigned short* __restrict__ gh,
                                                    unsigned short* __restrict__ gm,
                                                    unsigned short* __restrict__ gl) {
    __shared__ float As[16][68];
    __shared__ float Ws[16][68];
    int t = threadIdx.x;
    int z = blockIdx.z;
    const float* W = z ? W2 : Wv;
    int tx = t & 15, ty = t >> 4;
    int rowbase = blockIdx.x * 64, colbase = blockIdx.y * 64;
    float acc[4][4] = {};
    for (int k0 = 0; k0 < NC; k0 += 16) {
        {
            int r = t >> 2, ja = (t & 3) << 2;
            float4 a4 = *(const float4*)(A + (size_t)(rowbase + r)*NC + k0 + ja);
            As[ja+0][r] = a4.x; As[ja+1][r] = a4.y; As[ja+2][r] = a4.z; As[ja+3][r] = a4.w;
        }
        {
            int kr = t >> 4, jw = (t & 15) << 2;
            float4 w4 = *(const float4*)(W + (size_t)(k0 + kr)*NC + colbase + jw);
            *(float4*)&Ws[kr][jw] = w4;
        }
        __syncthreads();
        #pragma unroll
        for (int kk = 0; kk < 16; ++kk) {
            float4 av = *(const float4*)&As[kk][ty<<2];
            float4 wv = *(const float4*)&Ws[kk][tx<<2];
            float aa[4] = {av.x, av.y, av.z, av.w};
            float ww[4] = {wv.x, wv.y, wv.z, wv.w};
            #pragma unroll
            for (int i = 0; i < 4; ++i)
                #pragma unroll
                for (int j = 0; j < 4; ++j)
                    acc[i][j] += aa[i]*ww[j];
        }
        __syncthreads();
    }
    #pragma unroll
    for (int i = 0; i < 4; ++i) {
        size_t ro = (size_t)(rowbase + (ty<<2) + i)*NC + colbase + (tx<<2);
        if (z == 0) {
            *(float4*)(vmat + ro) = make_float4(acc[i][0], acc[i][1], acc[i][2], acc[i][3]);
        } else if constexpr (SPLIT) {
            us4 vh, vm, vl;
            #pragma unroll
            for (int j = 0; j < 4; ++j) {
                unsigned short h, mm, ll;
                split3(acc[i][j], h, mm, ll);
                vh[j] = h; vm[j] = mm; vl[j] = ll;
            }
            *(us4*)(gh + ro) = vh; *(us4*)(gm + ro) = vm; *(us4*)(gl + ro) = vl;
        } else {
            *(float4*)(GtF + ro) = make_float4(acc[i][0], acc[i][1], acc[i][2], acc[i][3]);
        }
    }
}

// ---------------- kernel 4: K x K overlap scores + top-16 per row ----------------
__global__ __launch_bounds__(256) void k_score_topk(const float* __restrict__ mu,
                                                    const float* __restrict__ Sg,
                                                    const float* __restrict__ maskp,
                                                    int* __restrict__ knn) {
    int b = blockIdx.x >> 9, i = blockIdx.x & 511;
    int t = threadIdx.x;
    __shared__ float swv[4];
    __shared__ int   swi[4];
    __shared__ int   winner;
    const float* mui = mu + (size_t)(b*NK + i)*3;
    const float* Sgi = Sg + (size_t)(b*NK + i)*9;
    float mi0 = mui[0], mi1 = mui[1], mi2 = mui[2];
    float S0 = Sgi[0], S1 = Sgi[1], S2 = Sgi[2], S4 = Sgi[4], S5 = Sgi[5], S8 = Sgi[8];
    float mski = maskp[b*NK + i];
    float cand[2];
    #pragma unroll
    for (int h = 0; h < 2; ++h) {
        int j = t + h*256;
        const float* muj = mu + (size_t)(b*NK + j)*3;
        const float* Sgj = Sg + (size_t)(b*NK + j)*9;
        float d0 = mi0-muj[0], d1 = mi1-muj[1], d2 = mi2-muj[2];
        float a00 = S0+Sgj[0]+1e-6f, a01 = S1+Sgj[1],       a02 = S2+Sgj[2];
        float a11 = S4+Sgj[4]+1e-6f, a12 = S5+Sgj[5],       a22 = S8+Sgj[8]+1e-6f;
        float c00 = a11*a22 - a12*a12;
        float c01 = a02*a12 - a01*a22;
        float c02 = a01*a12 - a02*a11;
        float c11 = a00*a22 - a02*a02;
        float c12 = a01*a02 - a00*a12;
        float c22 = a00*a11 - a01*a01;
        float det = a00*c00 + a01*c01 + a02*c02;
        float t0 = c00*d0 + c01*d1 + c02*d2;
        float t1 = c01*d0 + c11*d1 + c12*d2;
        float t2 = c02*d0 + c12*d1 + c22*d2;
        float maha = (d0*t0 + d1*t1 + d2*t2) / det;
        float score = -0.5f*(maha + logf(det));
        float mj = maskp[b*NK + j];
        cand[h] = (mski*mj < 0.5f) ? -1e9f : score;
    }
    int lane = t & 63, wv = t >> 6;
    for (int it = 0; it < NR; ++it) {
        float bv; int bi;
        if (cand[0] >= cand[1]) { bv = cand[0]; bi = t; }
        else                    { bv = cand[1]; bi = t + 256; }
        #pragma unroll
        for (int off = 32; off > 0; off >>= 1) {
            float v2 = __shfl_xor(bv, off);
            int   i2 = __shfl_xor(bi, off);
            if (v2 > bv || (v2 == bv && i2 < bi)) { bv = v2; bi = i2; }
        }
        if (lane == 0) { swv[wv] = bv; swi[wv] = bi; }
        __syncthreads();
        if (t == 0) {
            float B = swv[0]; int I = swi[0];
            #pragma unroll
            for (int w = 1; w < 4; ++w)
                if (swv[w] > B || (swv[w] == B && swi[w] < I)) { B = swv[w]; I = swi[w]; }
            knn[((size_t)(b*NK + i))*NR + it] = I;
            winner = I;
        }
        __syncthreads();
        int wn = winner;
        if (t == wn)        cand[0] = -INFINITY;
        if (t + 256 == wn)  cand[1] = -INFINITY;
    }
}

// -------- kernel 5: logits = q0 @ Gt^T via MFMA 3-split bf16 (6 passes) + argmax partials --------
template<bool SPLIT>
__global__ __launch_bounds__(256) void k_logits_mfma(const float* __restrict__ q0f,
                                                     const unsigned short* __restrict__ qh,
                                                     const unsigned short* __restrict__ qm,
                                                     const unsigned short* __restrict__ ql,
                                                     const float* __restrict__ GtF,
                                                     const unsigned short* __restrict__ gh,
                                                     const unsigned short* __restrict__ gm,
                                                     const unsigned short* __restrict__ gl,
                                                     const float* __restrict__ maskp,
                                                     float* __restrict__ logits,
                                                     float* __restrict__ pmaxv,
                                                     int*   __restrict__ pmaxi,
                                                     float* __restrict__ occ_part) {
    int bid = blockIdx.x;
    {   // zero occ_part [NSLICE][NB*NK] = 65536 floats across 512x256 threads
        int gid = bid * 256 + threadIdx.x;
        if (gid < NSLICE*NB*NK) occ_part[gid] = 0.f;
    }
    int wg = (bid & 7) * 64 + (bid >> 3);      // XCD-chunked swizzle (512 = 8*64)
    int b  = wg >> 8;
    int r8 = (wg >> 3) & 31;
    int cb = wg & 7;
    int rowbase = r8 << 7;
    int colbase = cb << 6;

    __shared__ __align__(16) unsigned short Ah[128][40];
    __shared__ __align__(16) unsigned short Am[128][40];
    __shared__ __align__(16) unsigned short Al[128][40];
    __shared__ __align__(16) unsigned short Bh[64][40];
    __shared__ __align__(16) unsigned short Bm2[64][40];
    __shared__ __align__(16) unsigned short Bl[64][40];
    __shared__ float rmv[128][2];
    __shared__ int   rmi[128][2];

    int t = threadIdx.x;
    int lane = t & 63, wv = t >> 6;
    int wr = wv >> 1, wc = wv & 1;
    int a = lane & 15, g = lane >> 4;

    size_t arow0 = (size_t)(b << 12) + rowbase;
    size_t brow0 = (size_t)(b << 9) + colbase;

    f32x4 acc[4][2];
    #pragma unroll
    for (int i = 0; i < 4; ++i)
        #pragma unroll
        for (int j = 0; j < 2; ++j)
            acc[i][j] = (f32x4){0.f, 0.f, 0.f, 0.f};

    for (int k0 = 0; k0 < NC; k0 += 32) {
        __syncthreads();
        if constexpr (SPLIT) {
            #pragma unroll
            for (int i = 0; i < 4; ++i) {       // A: 128 rows x 8 us4-segs
                int id = i*256 + t;
                int row = id >> 3, seg = id & 7;
                size_t go = (arow0 + row)*NC + k0 + (seg << 2);
                *(us4*)&Ah[row][seg << 2] = *(const us4*)(qh + go);
                *(us4*)&Am[row][seg << 2] = *(const us4*)(qm + go);
                *(us4*)&Al[row][seg << 2] = *(const us4*)(ql + go);
            }
            #pragma unroll
            for (int i = 0; i < 2; ++i) {       // B: 64 rows x 8 us4-segs
                int id = i*256 + t;
                int row = id >> 3, seg = id & 7;
                size_t go = (brow0 + row)*NC + k0 + (seg << 2);
                *(us4*)&Bh[row][seg << 2]  = *(const us4*)(gh + go);
                *(us4*)&Bm2[row][seg << 2] = *(const us4*)(gm + go);
                *(us4*)&Bl[row][seg << 2]  = *(const us4*)(gl + go);
            }
        } else {
            #pragma unroll
            for (int i = 0; i < 4; ++i) {       // A: 128 rows x 32 f32 = 1024 float4
                int id = i*256 + t;
                int row = id >> 3, seg = id & 7;
                float4 v = *(const float4*)(q0f + (arow0 + row)*NC + k0 + (seg << 2));
                unsigned short h0,m0,l0,h1,m1,l1,h2,m2,l2,h3,m3,l3;
                split3(v.x, h0, m0, l0); split3(v.y, h1, m1, l1);
                split3(v.z, h2, m2, l2); split3(v.w, h3, m3, l3);
                *(us4*)&Ah[row][seg << 2] = (us4){h0, h1, h2, h3};
                *(us4*)&Am[row][seg << 2] = (us4){m0, m1, m2, m3};
                *(us4*)&Al[row][seg << 2] = (us4){l0, l1, l2, l3};
            }
            #pragma unroll
            for (int i = 0; i < 2; ++i) {       // B: 64 rows x 32 f32 = 512 float4
                int id = i*256 + t;
                int row = id >> 3, seg = id & 7;
                float4 v = *(const float4*)(GtF + (brow0 + row)*NC + k0 + (seg << 2));
                unsigned short h0,m0,l0,h1,m1,l1,h2,m2,l2,h3,m3,l3;
                split3(v.x, h0, m0, l0); split3(v.y, h1, m1, l1);
                split3(v.z, h2, m2, l2); split3(v.w, h3, m3, l3);
                *(us4*)&Bh[row][seg << 2]  = (us4){h0, h1, h2, h3};
                *(us4*)&Bm2[row][seg << 2] = (us4){m0, m1, m2, m3};
                *(us4*)&Bl[row][seg << 2]  = (us4){l0, l1, l2, l3};
            }
        }
        __syncthreads();
        short8 afh[4], afm[4], afl[4];
        #pragma unroll
        for (int fr = 0; fr < 4; ++fr) {
            int r = (wr << 6) + (fr << 4) + a;
            afh[fr] = *(const short8*)&Ah[r][g << 3];
            afm[fr] = *(const short8*)&Am[r][g << 3];
            afl[fr] = *(const short8*)&Al[r][g << 3];
        }
        #pragma unroll
        for (int fc = 0; fc < 2; ++fc) {
            int c = (wc << 5) + (fc << 4) + a;
            short8 bh = *(const short8*)&Bh[c][g << 3];
            short8 bm = *(const short8*)&Bm2[c][g << 3];
            short8 bl = *(const short8*)&Bl[c][g << 3];
            #pragma unroll
            for (int fr = 0; fr < 4; ++fr) {
                acc[fr][fc] = __builtin_amdgcn_mfma_f32_16x16x32_bf16(afh[fr], bh, acc[fr][fc], 0, 0, 0);
                acc[fr][fc] = __builtin_amdgcn_mfma_f32_16x16x32_bf16(afh[fr], bm, acc[fr][fc], 0, 0, 0);
                acc[fr][fc] = __builtin_amdgcn_mfma_f32_16x16x32_bf16(afm[fr], bh, acc[fr][fc], 0, 0, 0);
                acc[fr][fc] = __builtin_amdgcn_mfma_f32_16x16x32_bf16(afh[fr], bl, acc[fr][fc], 0, 0, 0);
                acc[fr][fc] = __builtin_amdgcn_mfma_f32_16x16x32_bf16(afl[fr], bh, acc[fr][fc], 0, 0, 0);
                acc[fr][fc] = __builtin_amdgcn_mfma_f32_16x16x32_bf16(afm[fr], bm, acc[fr][fc], 0, 0, 0);
            }
        }
    }
    // epilogue: scale, store logits, masked per-row argmax partial
    float mk[2];
    #pragma unroll
    for (int fc = 0; fc < 2; ++fc)
        mk[fc] = (maskp[(b << 9) + colbase + (wc << 5) + (fc << 4) + a] - 1.0f) * 1e9f;
    int colg0 = colbase + (wc << 5) + a;
    #pragma unroll
    for (int fr = 0; fr < 4; ++fr) {
        #pragma unroll
        for (int reg = 0; reg < 4; ++reg) {
            int rloc = (wr << 6) + (fr << 4) + (g << 2) + reg;
            size_t rowg = (size_t)(b << 12) + rowbase + rloc;
            float v0 = acc[fr][0][reg] * INV_SQRT_C;
            float v1 = acc[fr][1][reg] * INV_SQRT_C;
            logits[rowg * NK + colg0]      = v0;
            logits[rowg * NK + colg0 + 16] = v1;
            float bv = v0 + mk[0]; int bc = colg0;
            float w1 = v1 + mk[1];
            if (w1 > bv) { bv = w1; bc = colg0 + 16; }
            #pragma unroll
            for (int off = 1; off < 16; off <<= 1) {
                float v2 = __shfl_xor(bv, off);
                int   c2 = __shfl_xor(bc, off);
                if (v2 > bv || (v2 == bv && c2 < bc)) { bv = v2; bc = c2; }
            }
            if (a == 0) { rmv[rloc][wc] = bv; rmi[rloc][wc] = bc; }
        }
    }
    __syncthreads();
    if (t < 128) {
        float v0 = rmv[t][0], v1 = rmv[t][1];
        int   c0 = rmi[t][0], c1 = rmi[t][1];
        float bv = v0; int bc = c0;
        if (v1 > bv) { bv = v1; bc = c1; }     // wc=1 cols are larger: strict >
        pmaxv[(((size_t)(b << 3) + cb) << 12) + rowbase + t] = bv;
        pmaxi[(((size_t)(b << 3) + cb) << 12) + rowbase + t] = bc;
    }
}

// ---------------- kernel 6: gathered attention epilogue — 16 rows/block ----------------
__global__ __launch_bounds__(256) void k_final(const float* __restrict__ logits,
                                               const float* __restrict__ vmat,
                                               const float* __restrict__ mu,
                                               const float* __restrict__ Sg,
                                               const float* __restrict__ node_mask,
                                               const float* __restrict__ pmaxv,
                                               const int*   __restrict__ pmaxi,
                                               const int* __restrict__ knn,
                                               float* __restrict__ out_s0,
                                               float* __restrict__ out_mu0,
                                               float* __restrict__ out_Sig0,
                                               float* __restrict__ out_Bl,
                                               float* __restrict__ occ_part,
                                               float* __restrict__ loss_part) {
    int t = threadIdx.x;
    int rowbase = blockIdx.x << 4;
    int b = rowbase >> 12;
    int l  = t & 63;
    int sub = l >> 4, ll = l & 15;
    int r = ((t >> 6) << 2) + sub;          // 0..15, this thread's row
    int grow = rowbase + r;
    __shared__ float wl[16][17];
    __shared__ int   pidx[16][17];
    __shared__ float lred[16];
    __shared__ float msk[16];
    __shared__ int   j0s[16];

    if (t < 16) {                            // combine 8 argmax partials -> j0
        int rowb = (rowbase & 4095) + t;
        float bv = -INFINITY; int bj = 0;
        #pragma unroll
        for (int cbk = 0; cbk < 8; ++cbk) {
            size_t idx = (((size_t)(b << 3) + cbk) << 12) + rowb;
            float v = pmaxv[idx];
            if (v > bv) { bv = v; bj = pmaxi[idx]; }
        }
        j0s[t] = bj;
    }
    __syncthreads();

    float m = node_mask[grow];
    int p = knn[((size_t)(b*NK + j0s[r]))*NR + ll];
    float v = logits[(size_t)grow*NK + p];
    float mx = v;
    #pragma unroll
    for (int off = 8; off > 0; off >>= 1) mx = fmaxf(mx, __shfl_xor(mx, off));
    float e = expf(v - mx);
    float sme = e;
    #pragma unroll
    for (int off = 8; off > 0; off >>= 1) sme += __shfl_xor(sme, off);
    float w = e / sme;
    wl[r][ll] = w;
    pidx[r][ll] = p;
    out_Bl[(size_t)rowbase*NR + t] = w;     // r*16+ll == t

    const float* mur = mu + (size_t)(b*NK + p)*3;
    const float* Sgr = Sg + (size_t)(b*NK + p)*9;
    float mr0 = mur[0], mr1 = mur[1], mr2 = mur[2];
    float m0 = w*mr0, m1 = w*mr1, m2 = w*mr2;
    #pragma unroll
    for (int off = 8; off > 0; off >>= 1) {
        m0 += __shfl_xor(m0, off); m1 += __shfl_xor(m1, off); m2 += __shfl_xor(m2, off);
    }
    float d0 = mr0-m0, d1 = mr1-m1, d2 = mr2-m2;
    float a00 = Sgr[0], a01 = Sgr[1], a02 = Sgr[2];
    float a11 = Sgr[4], a12 = Sgr[5], a22 = Sgr[8];
    float p00 = w*(a00 + d0*d0), p01 = w*(a01 + d0*d1), p02 = w*(a02 + d0*d2);
    float p11 = w*(a11 + d1*d1), p12 = w*(a12 + d1*d2), p22 = w*(a22 + d2*d2);
    #pragma unroll
    for (int off = 8; off > 0; off >>= 1) {
        p00 += __shfl_xor(p00, off); p01 += __shfl_xor(p01, off); p02 += __shfl_xor(p02, off);
        p11 += __shfl_xor(p11, off); p12 += __shfl_xor(p12, off); p22 += __shfl_xor(p22, off);
    }
    float c00 = a11*a22 - a12*a12;
    float c01 = a02*a12 - a01*a22;
    float c02 = a01*a12 - a02*a11;
    float c11 = a00*a22 - a02*a02;
    float c12 = a01*a02 - a00*a12;
    float c22 = a00*a11 - a01*a01;
    float det = a00*c00 + a01*c01 + a02*c02;
    float t0 = c00*d0 + c01*d1 + c02*d2;
    float t1 = c01*d0 + c11*d1 + c12*d2;
    float t2 = c02*d0 + c12*d1 + c22*d2;
    float maha = (d0*t0 + d1*t1 + d2*t2) / det;
    float score = -0.5f*(maha + logf(det));
    float lp = w*score;
    #pragma unroll
    for (int off = 8; off > 0; off >>= 1) lp += __shfl_xor(lp, off);
    if (ll == 0) {
        out_mu0[(size_t)grow*3+0] = m0;
        out_mu0[(size_t)grow*3+1] = m1;
        out_mu0[(size_t)grow*3+2] = m2;
        float* o = out_Sig0 + (size_t)grow*9;
        o[0]=p00+F_JITTER; o[1]=p01;          o[2]=p02;
        o[3]=p01;          o[4]=p11+F_JITTER; o[5]=p12;
        o[6]=p02;          o[7]=p12;          o[8]=p22+F_JITTER;
        lred[r] = m*lp;
        msk[r] = m;
    }
    atomicAdd(&occ_part[(size_t)(blockIdx.x & (NSLICE-1))*(NB*NK) + b*NK + p], w*m);
    __syncthreads();
    if (t == 0) {
        float s = 0.f;
        #pragma unroll
        for (int i = 0; i < 16; ++i) s += lred[i];
        loss_part[blockIdx.x] = s;
    }
    const float4* vb = (const float4*)(vmat + (size_t)b*NK*NC);
    #pragma unroll
    for (int it = 0; it < 6; ++it) {
        int id = it*256 + t;
        int row = id / 96;
        int col = id - row*96;
        float4 acc4 = make_float4(0.f, 0.f, 0.f, 0.f);
        #pragma unroll
        for (int r2 = 0; r2 < NR; ++r2) {
            float ww = wl[row][r2];
            float4 vv = vb[(size_t)pidx[row][r2]*96 + col];
            acc4.x += ww*vv.x; acc4.y += ww*vv.y; acc4.z += ww*vv.z; acc4.w += ww*vv.w;
        }
        float mm = msk[row];
        acc4.x *= mm; acc4.y *= mm; acc4.z *= mm; acc4.w *= mm;
        ((float4*)(out_s0 + (size_t)(rowbase + row)*NC))[col] = acc4;
    }
}

// ---------------- kernel 7: occ-slice reduce + normalize + loss ----------------
__global__ __launch_bounds__(1024) void k_finalize(const float* __restrict__ occ_part,
                                                   const float* __restrict__ Lsum,
                                                   const float* __restrict__ loss_part,
                                                   float* __restrict__ out_occn,
                                                   float* __restrict__ out_loss) {
    int t = threadIdx.x;
    __shared__ float red[1024];
    float s = 0.f;
    for (int sl = 0; sl < NSLICE; ++sl) s += occ_part[(size_t)sl*(NB*NK) + t];
    red[t] = s; __syncthreads();
    for (int w = 256; w > 0; w >>= 1) {
        if ((t & 511) < w) red[t] += red[t+w];
        __syncthreads();
    }
    float tot = red[t & 512];
    float occn = s / fmaxf(tot, 1e-9f);
    __syncthreads();
    out_occn[t] = occn;
    float lp = (t < 512) ? loss_part[t] : 0.f;
    red[t] = lp; __syncthreads();
    for (int w = 512; w > 0; w >>= 1) {
        if (t < w) red[t] += red[t+w];
        __syncthreads();
    }
    if (t == 0) {
        float dnm = fmaxf(Lsum[0] + Lsum[1], 1.0f);
        out_loss[0] = -(red[0] / dnm);
    }
}

extern "C" void kernel_launch(void* const* d_in, const int* in_sizes, int n_in,
                              void* d_out, int out_size, void* d_ws, size_t ws_size,
                              hipStream_t stream) {
    const float* s_parent   = (const float*)d_in[0];
    const float* mu_parent  = (const float*)d_in[1];
    const float* Sig_parent = (const float*)d_in[2];
    const float* mask_par   = (const float*)d_in[3];
    const float* node_mask  = (const float*)d_in[4];
    const int*   res_idx    = (const int*)d_in[5];
    const float* Bm         = (const float*)d_in[6];
    const float* Wq         = (const float*)d_in[7];
    const float* Wk         = (const float*)d_in[8];
    const float* Wv         = (const float*)d_in[9];
    const float* ln_g       = (const float*)d_in[10];
    const float* ln_b       = (const float*)d_in[11];

    const bool G = (ws_size >= (43ull << 20));   // pre-split path needs 40.6 MB; fallback 33.6 MB (proven)

    float* ws = (float*)d_ws;
    const size_t SZ_A    = G ? 4718592 : 3145728;        // q0 splits (3 bf16 planes) | q0 fp32
    const size_t OFF_LOG = 0;                            // logits 4,194,304 f
    const size_t OFF_A   = OFF_LOG + 4194304;
    const size_t OFF_MISC= OFF_A + SZ_A;                 // 262,144 f: W2(early) / pmax+knn+occ(late)
    const size_t OFF_V   = OFF_MISC + 262144;            // vmat 393,216 f
    const size_t OFF_GT  = OFF_V + 393216;               // Gt: splits 589,824 f | fp32 393,216 f
    const size_t OFF_SM  = OFF_GT + (G ? 589824 : 393216);

    float*          logits = ws + OFF_LOG;
    float*          q0f    = ws + OFF_A;                               // !G
    unsigned short* qh     = (unsigned short*)(ws + OFF_A);            // G
    unsigned short* qm     = qh + (size_t)NB*NN*NC;
    unsigned short* ql     = qm + (size_t)NB*NN*NC;
    float*          W2     = ws + OFF_MISC;                            // early life
    float*          pmaxv  = ws + OFF_MISC;                            // late life
    int*            pmaxi  = (int*)(ws + OFF_MISC + 65536);
    int*            knn    = (int*)(ws + OFF_MISC + 131072);
    float*          occ_part = ws + OFF_MISC + 147456;
    float*          vmat   = ws + OFF_V;
    float*          GtF    = ws + OFF_GT;                              // !G
    unsigned short* gh     = (unsigned short*)(ws + OFF_GT);           // G
    unsigned short* gm     = gh + (size_t)NB*NK*NC;
    unsigned short* gl     = gm + (size_t)NB*NK*NC;
    float*          Lsum   = ws + OFF_SM;
    float*          lpart  = ws + OFF_SM + 16;

    float* out      = (float*)d_out;
    float* out_s0   = out;
    float* out_mu0  = out      + (size_t)NB*NN*NC;
    float* out_Sig0 = out_mu0  + (size_t)NB*NN*3;
    float* out_Bl   = out_Sig0 + (size_t)NB*NN*9;
    float* out_occn = out_Bl   + (size_t)NB*NN*NR;
    float* out_loss = out_occn + (size_t)NB*NK;

    (void)in_sizes; (void)n_in; (void)out_size;

    k_masksum<<<NB, 256, 0, stream>>>(node_mask, Lsum);
    if (G) k_q0<true ><<<(NB*NN)/4, 256, 0, stream>>>(res_idx, node_mask, Bm, ln_g, ln_b, Lsum, q0f, qh, qm, ql);
    else   k_q0<false><<<(NB*NN)/4, 256, 0, stream>>>(res_idx, node_mask, Bm, ln_g, ln_b, Lsum, q0f, qh, qm, ql);
    k_gemm384_bt<<<dim3(NC/64, NC/64), 256, 0, stream>>>(Wk, Wq, W2);   // W2 = Wk @ Wq^T
    if (G) k_gemm_dualz<true ><<<dim3((NB*NK)/64, NC/64, 2), 256, 0, stream>>>(s_parent, Wv, W2, vmat, GtF, gh, gm, gl);
    else   k_gemm_dualz<false><<<dim3((NB*NK)/64, NC/64, 2), 256, 0, stream>>>(s_parent, Wv, W2, vmat, GtF, gh, gm, gl);
    // W2 region is dead from here; topk/logits reuse it for knn/pmax/occ
    k_score_topk<<<NB*NK, 256, 0, stream>>>(mu_parent, Sig_parent, mask_par, knn);
    if (G) k_logits_mfma<true ><<<512, 256, 0, stream>>>(q0f, qh, qm, ql, GtF, gh, gm, gl,
                                                         mask_par, logits, pmaxv, pmaxi, occ_part);
    else   k_logits_mfma<false><<<512, 256, 0, stream>>>(q0f, qh, qm, ql, GtF, gh, gm, gl,
                                                         mask_par, logits, pmaxv, pmaxi, occ_part);
    k_final<<<(NB*NN)/16, 256, 0, stream>>>(logits, vmat, mu_parent, Sig_parent, node_mask,
                                            pmaxv, pmaxi, knn, out_s0, out_mu0, out_Sig0,
                                            out_Bl, occ_part, lpart);
    k_finalize<<<1, 1024, 0, stream>>>(occ_part, Lsum, lpart, out_occn, out_loss);
}